// Round 5
// baseline (908.747 us; speedup 1.0000x reference)
//
#include <hip/hip_runtime.h>
#include <math.h>

#define HD 128      // hidden dim (= F_IN)
#define ED 16       // edge feat dim
#define NG 64       // num graphs
#define NC 10       // num classes

typedef short bf16x8 __attribute__((ext_vector_type(8)));
typedef float f32x4 __attribute__((ext_vector_type(4)));

__device__ __forceinline__ unsigned short f2b(float x){
  unsigned u = __float_as_uint(x);
  unsigned r = (u + 0x7fffu + ((u >> 16) & 1u)) >> 16;
  return (unsigned short)r;
}
__device__ __forceinline__ float blo(unsigned p){ return __uint_as_float(p << 16); }
__device__ __forceinline__ float bhi(unsigned p){ return __uint_as_float(p & 0xffff0000u); }

// ---------------- CSR build ----------------
__global__ void k_hist(const int* __restrict__ dst, int* __restrict__ deg, int E){
  int e = blockIdx.x*blockDim.x + threadIdx.x;
  if(e<E) atomicAdd(&deg[dst[e]], 1);
}

__global__ __launch_bounds__(64) void k_bsum(const int* __restrict__ deg, int* __restrict__ bsum, int N){
  int b = blockIdx.x, t = threadIdx.x;
  int i = b*256 + t*4;
  int s = 0;
  if(i+3 < N){ int4 v = *(const int4*)&deg[i]; s = v.x+v.y+v.z+v.w; }
  else { for(int k=0;k<4;k++) if(i+k<N) s += deg[i+k]; }
  #pragma unroll
  for(int o=32;o;o>>=1) s += __shfl_xor(s,o);
  if(t==0) bsum[b] = s;
}

__global__ __launch_bounds__(1024) void k_bscan(const int* __restrict__ bsum, int* __restrict__ bbase,
                                                int* __restrict__ offs, int N, int nb){
  __shared__ int sh[1024];
  int t = threadIdx.x;
  int v = (t < nb) ? bsum[t] : 0;
  sh[t] = v; __syncthreads();
  for(int o=1;o<1024;o<<=1){ int u = (t>=o)?sh[t-o]:0; __syncthreads(); sh[t]+=u; __syncthreads(); }
  if(t < nb) bbase[t] = sh[t] - v;
  if(t == 1023) offs[N] = sh[1023];
}

__global__ __launch_bounds__(256) void k_bprop(const int* __restrict__ deg, const int* __restrict__ bbase,
                                               int* __restrict__ offs, int* __restrict__ cursor, int N){
  __shared__ int sh[256];
  int b = blockIdx.x, t = threadIdx.x;
  int i = b*256 + t;
  int v = (i<N) ? deg[i] : 0;
  sh[t] = v; __syncthreads();
  for(int o=1;o<256;o<<=1){ int u = (t>=o)?sh[t-o]:0; __syncthreads(); sh[t]+=u; __syncthreads(); }
  if(i<N){ int o_ = bbase[b] + sh[t] - v; offs[i] = o_; cursor[i] = o_; }
}

__global__ void k_scatter(const int* __restrict__ src, const int* __restrict__ dst,
                          int* __restrict__ cursor, int* __restrict__ pos,
                          int* __restrict__ src_csr, int* __restrict__ dst_csr, int E){
  int e = blockIdx.x*blockDim.x + threadIdx.x;
  if(e<E){
    int d = dst[e];
    int p = atomicAdd(&cursor[d], 1);
    pos[e] = p;
    src_csr[p] = src[e];
    dst_csr[p] = d;
  }
}

__global__ void k_eq(const float* __restrict__ ef,
                     const float* __restrict__ a1e, const float* __restrict__ a2e, const float* __restrict__ a3e,
                     const int* __restrict__ pos, float* __restrict__ q, int E){
  int e = blockIdx.x*blockDim.x + threadIdx.x;
  if(e>=E) return;
  const float* f = &ef[(size_t)e*ED];
  float q1=0.f, q2=0.f, q3=0.f;
  #pragma unroll
  for(int i=0;i<ED;i++){
    float fv = f[i];
    q1 = fmaf(fv, a1e[i], q1);
    q2 = fmaf(fv, a2e[i], q2);
    q3 = fmaf(fv, a3e[i], q3);
  }
  int j = pos[e];
  q[j] = q1; q[(size_t)E + j] = q2; q[2*(size_t)E + j] = q3;
}

// ---------------- fp32 -> bf16 cast into chunked layout [4][N][32] ----------------
__global__ void k_cast(const float* __restrict__ x, unsigned* __restrict__ xc, int N){
  int idx = blockIdx.x*blockDim.x + threadIdx.x;   // one per 8 elements
  if(idx >= N*16) return;
  int i2 = idx*8;
  int node = i2 >> 7;
  int col0 = i2 & 127;
  float4 v0 = *(const float4*)&x[(size_t)node*HD + col0];
  float4 v1 = *(const float4*)&x[(size_t)node*HD + col0 + 4];
  uint4 o;
  o.x = f2b(v0.x) | ((unsigned)f2b(v0.y)<<16);
  o.y = f2b(v0.z) | ((unsigned)f2b(v0.w)<<16);
  o.z = f2b(v1.x) | ((unsigned)f2b(v1.y)<<16);
  o.w = f2b(v1.z) | ((unsigned)f2b(v1.w)<<16);
  int chunk = col0 >> 5;
  int wo = (col0 & 31) >> 1;   // uint offset within 16-uint row-chunk
  *(uint4*)&xc[((size_t)chunk*N + node)*16 + wo] = o;
}

// ---------------- W -> B-fragment-swizzled bf16 (all 3 layers) ----------------
__global__ __launch_bounds__(256) void k_wswiz(const float* __restrict__ W1, const float* __restrict__ W2,
                        const float* __restrict__ W3, unsigned short* __restrict__ Wb){
  int idx = blockIdx.x*256 + threadIdx.x;    // 3 * 2048
  if(idx >= 3*2048) return;
  int layer = idx >> 11;
  int r = idx & 2047;
  const float* W = (layer==0)?W1:((layer==1)?W2:W3);
  int lane = r & 63, tile = r >> 6;
  int kt = tile >> 3, nt = tile & 7;
  int qq = lane >> 4, cc = lane & 15;
  int kbase = kt*32 + qq*8;
  int col = nt*16 + cc;
  unsigned short tmp[8];
  #pragma unroll
  for(int j=0;j<8;j++) tmp[j] = f2b(W[(size_t)(kbase+j)*HD + col]);
  uint4 o;
  o.x = tmp[0]|((unsigned)tmp[1]<<16); o.y = tmp[2]|((unsigned)tmp[3]<<16);
  o.z = tmp[4]|((unsigned)tmp[5]<<16); o.w = tmp[6]|((unsigned)tmp[7]<<16);
  *(uint4*)&Wb[(size_t)idx*8] = o;
}

// ---------------- MFMA GEMM on chunked layouts, fused pdots ----------------
// A, Z in chunked layout [4][M][32] bf16 (16 uints per row-chunk).
__global__ __launch_bounds__(256) void k_gemm_mfma(
    const unsigned* __restrict__ Ac,
    const unsigned short* __restrict__ Wb,
    unsigned short* __restrict__ Zc,
    const float* __restrict__ avec,
    float* __restrict__ ps, float* __restrict__ pd, int M)
{
  int tid = threadIdx.x;
  int w = tid >> 6, lane = tid & 63;
  int q = lane >> 4, c = lane & 15;
  int rowbase = blockIdx.x*128 + w*32;
  f32x4 acc[2][8];
  #pragma unroll
  for(int t=0;t<2;t++)
    #pragma unroll
    for(int n=0;n<8;n++) acc[t][n] = (f32x4){0.f,0.f,0.f,0.f};

  int r0 = rowbase + c;      if(r0 > M-1) r0 = M-1;
  int r1 = rowbase + 16 + c; if(r1 > M-1) r1 = M-1;
  #pragma unroll
  for(int kt=0; kt<4; kt++){
    // cols kt*32 + q*8 .. +7  ->  chunk kt, uint offset 4q
    bf16x8 a0 = __builtin_bit_cast(bf16x8, *(const uint4*)&Ac[((size_t)kt*M + r0)*16 + 4*q]);
    bf16x8 a1 = __builtin_bit_cast(bf16x8, *(const uint4*)&Ac[((size_t)kt*M + r1)*16 + 4*q]);
    #pragma unroll
    for(int n=0;n<8;n++){
      bf16x8 b = __builtin_bit_cast(bf16x8, *(const uint4*)&Wb[(((size_t)(kt*8+n))*64 + lane)*8]);
      acc[0][n] = __builtin_amdgcn_mfma_f32_16x16x32_bf16(a0, b, acc[0][n], 0,0,0);
      acc[1][n] = __builtin_amdgcn_mfma_f32_16x16x32_bf16(a1, b, acc[1][n], 0,0,0);
    }
  }
  float asv[8], adv[8];
  #pragma unroll
  for(int n=0;n<8;n++){ asv[n] = avec[n*16+c]; adv[n] = avec[HD + n*16+c]; }
  #pragma unroll
  for(int t=0;t<2;t++){
    #pragma unroll
    for(int r=0;r<4;r++){
      int grow = rowbase + t*16 + 4*q + r;
      bool ok = grow < M;
      #pragma unroll
      for(int n=0;n<8;n++){
        if(ok){
          // col n*16+c -> chunk n>>1, within (n&1)*16 + c
          Zc[(((size_t)(n>>1))*M + grow)*32 + (n&1)*16 + c] = f2b(acc[t][n][r]);
        }
      }
      float pp = 0.f, dd = 0.f;
      #pragma unroll
      for(int n=0;n<8;n++){ pp = fmaf(acc[t][n][r], asv[n], pp); dd = fmaf(acc[t][n][r], adv[n], dd); }
      #pragma unroll
      for(int o=1;o<16;o<<=1){ pp += __shfl_xor(pp,o); dd += __shfl_xor(dd,o); }
      if(ok && c==0){ ps[grow] = pp; pd[grow] = dd; }
    }
  }
}

// ---------------- edge logits in CSR order (leaky 0.2) ----------------
__global__ void k_logits(const float* __restrict__ ps, const float* __restrict__ pd,
                         const int* __restrict__ src_csr, const int* __restrict__ dst_csr,
                         const float* __restrict__ q, float* __restrict__ lg, int E){
  int j = blockIdx.x*blockDim.x + threadIdx.x;
  if(j>=E) return;
  float l = ps[src_csr[j]] + pd[dst_csr[j]] + q[j];
  lg[j] = (l >= 0.f) ? l : 0.2f*l;
}

// ---------------- per-node softmax: store unnormalized exp + 1/sum ----------------
__global__ __launch_bounds__(256) void k_soft(const float* __restrict__ lg,
                                              const int* __restrict__ offs,
                                              float* __restrict__ wbuf,
                                              float* __restrict__ invb, int N){
  int wid = blockIdx.x*4 + (threadIdx.x>>6);
  int lane = threadIdx.x & 63;
  if(wid >= N) return;
  int d0 = offs[wid], d1 = offs[wid+1];
  float m = -INFINITY;
  for(int j=d0+lane; j<d1; j+=64) m = fmaxf(m, lg[j]);
  #pragma unroll
  for(int o=32;o;o>>=1) m = fmaxf(m, __shfl_xor(m,o));
  float s = 0.f;
  for(int j=d0+lane; j<d1; j+=64){ float e = __expf(lg[j]-m); wbuf[j]=e; s += e; }
  #pragma unroll
  for(int o=32;o;o>>=1) s += __shfl_xor(s,o);
  if(lane==0) invb[wid] = (d1 > d0) ? 1.0f/s : 0.0f;
}

// ---------------- chunked aggregate: one 32-col chunk, L2-resident z table ----------------
__global__ __launch_bounds__(256) void k_aggc(const unsigned* __restrict__ zc,
                                              const float* __restrict__ wbuf,
                                              const int* __restrict__ offs,
                                              const int* __restrict__ src_csr,
                                              const float* __restrict__ invb,
                                              unsigned* __restrict__ hc, int N, int chunk){
  int wid = blockIdx.x*4 + (threadIdx.x>>6);
  int lane = threadIdx.x & 63;
  if(wid >= N) return;
  int q = lane >> 4, c = lane & 15;
  int d0 = offs[wid], d1 = offs[wid+1];
  const unsigned* zt = zc + (size_t)chunk*N*16;
  float acc0 = 0.f, acc1 = 0.f;
  for(int j=d0; j<d1; j+=4){
    int jq = j + q;
    bool v = jq < d1;
    int e = v ? jq : (d1-1);
    float w = v ? wbuf[e] : 0.f;
    int u = src_csr[e];
    unsigned P = zt[(size_t)u*16 + c];
    acc0 = fmaf(w, blo(P), acc0);
    acc1 = fmaf(w, bhi(P), acc1);
  }
  acc0 += __shfl_xor(acc0,16); acc0 += __shfl_xor(acc0,32);
  acc1 += __shfl_xor(acc1,16); acc1 += __shfl_xor(acc1,32);
  if(q==0){
    float inv = invb[wid];
    float h0 = fmaxf(acc0*inv, 0.f), h1 = fmaxf(acc1*inv, 0.f);
    hc[((size_t)chunk*N + wid)*16 + c] = (unsigned)f2b(h0) | ((unsigned)f2b(h1)<<16);
  }
}

// ---------------- readout with in-wave att (chunked bf16 h) ----------------
#define RCH 8
__global__ __launch_bounds__(64) void k_readout(const unsigned* __restrict__ hc,
                                                const int* __restrict__ gid,
                                                const float* __restrict__ watt,
                                                const float* __restrict__ batt,
                                                float* __restrict__ hg, int N){
  int g = blockIdx.x / RCH;
  int chunkb = blockIdx.x % RCH;
  int t = threadIdx.x;           // 64 = 1 wave
  int ch = t >> 4, u = t & 15;   // thread owns cols ch*32+2u, +1
  int lo=0, hi=N;
  while(lo<hi){ int mid=(lo+hi)>>1; if(gid[mid] < g) lo=mid+1; else hi=mid; }
  int start = lo; lo = start; hi = N;
  while(lo<hi){ int mid=(lo+hi)>>1; if(gid[mid] < g+1) lo=mid+1; else hi=mid; }
  int end = lo;
  int len = end - start;
  int c0 = start + (int)(((long long)len * chunkb) / RCH);
  int c1 = start + (int)(((long long)len * (chunkb+1)) / RCH);
  float w0 = watt[ch*32 + 2*u], w1 = watt[ch*32 + 2*u + 1];
  float b = batt[0];
  float acc0 = 0.f, acc1 = 0.f;
  for(int v=c0; v<c1; v++){
    unsigned P = hc[((size_t)ch*N + v)*16 + u];
    float h0 = blo(P), h1 = bhi(P);
    float tp = h0*w0 + h1*w1;
    #pragma unroll
    for(int o=32;o;o>>=1) tp += __shfl_xor(tp,o);
    float lv = tp + b;
    float att = __expf((lv >= 0.f) ? lv : 0.01f*lv);
    acc0 = fmaf(att, h0, acc0);
    acc1 = fmaf(att, h1, acc1);
  }
  atomicAdd(&hg[g*HD + ch*32 + 2*u],     acc0);
  atomicAdd(&hg[g*HD + ch*32 + 2*u + 1], acc1);
}

// ---------------- per-graph node counts ----------------
__global__ __launch_bounds__(64) void k_cnt(const int* __restrict__ gid, float* __restrict__ cnt, int N){
  int g = threadIdx.x;
  if(g >= NG) return;
  int lo=0, hi=N;
  while(lo<hi){ int mid=(lo+hi)>>1; if(gid[mid] < g) lo=mid+1; else hi=mid; }
  int start = lo; lo = start; hi = N;
  while(lo<hi){ int mid=(lo+hi)>>1; if(gid[mid] < g+1) lo=mid+1; else hi=mid; }
  cnt[g] = (float)(lo - start);
}

// ---------------- final classifier + log_softmax ----------------
__global__ __launch_bounds__(256) void k_final(const float* __restrict__ hg,
                                               const float* __restrict__ cnt,
                                               const float* __restrict__ Wc,
                                               const float* __restrict__ bc,
                                               float* __restrict__ out){
  __shared__ float y[NG][NC];
  int tid = threadIdx.x;
  for(int idx=tid; idx<NG*NC; idx+=256){
    int g = idx / NC, c = idx % NC;
    float invc = 1.f / fmaxf(cnt[g], 1.f);
    float s = bc[c];
    #pragma unroll
    for(int part=0; part<3; part++){
      const float* row = &hg[part*NG*HD + g*HD];
      for(int f=0; f<HD; f++) s = fmaf(row[f]*invc, Wc[(part*HD+f)*NC + c], s);
    }
    y[g][c] = s;
  }
  __syncthreads();
  if(tid < NG){
    float mx = -INFINITY;
    #pragma unroll
    for(int c=0;c<NC;c++) mx = fmaxf(mx, y[tid][c]);
    float s = 0.f;
    #pragma unroll
    for(int c=0;c<NC;c++) s += __expf(y[tid][c] - mx);
    float ls = logf(s);
    #pragma unroll
    for(int c=0;c<NC;c++) out[tid*NC + c] = y[tid][c] - mx - ls;
  }
}

// ---------------- host ----------------
extern "C" void kernel_launch(void* const* d_in, const int* in_sizes, int n_in,
                              void* d_out, int out_size, void* d_ws, size_t ws_size,
                              hipStream_t stream) {
  const float* x     = (const float*)d_in[0];
  const float* efeat = (const float*)d_in[1];
  const int*   src   = (const int*)d_in[2];
  const int*   dst   = (const int*)d_in[3];
  const int*   gid   = (const int*)d_in[4];
  const float* W1    = (const float*)d_in[5];
  const float* a1    = (const float*)d_in[6];
  const float* W2    = (const float*)d_in[7];
  const float* a2    = (const float*)d_in[8];
  const float* W3    = (const float*)d_in[9];
  const float* a3    = (const float*)d_in[10];
  const float* watt  = (const float*)d_in[11];
  const float* batt  = (const float*)d_in[12];
  const float* Wc    = (const float*)d_in[13];
  const float* bc    = (const float*)d_in[14];
  float* out = (float*)d_out;

  int N = in_sizes[4];
  int E = in_sizes[2];

  char* p = (char*)d_ws;
  auto alloc = [&](size_t bytes)->void*{
    void* r = (void*)p;
    p += (bytes + 255) & ~(size_t)255;
    return r;
  };
  unsigned* Xc = (unsigned*)alloc((size_t)N*HD*2);   // x bf16 chunked [4][N][32]
  unsigned* Hc = (unsigned*)alloc((size_t)N*HD*2);   // h bf16 chunked
  unsigned* Zc = (unsigned*)alloc((size_t)N*HD*2);   // z bf16 chunked
  unsigned short* Wball = (unsigned short*)alloc((size_t)3*2048*8*2);
  float* ps      = (float*)alloc((size_t)N*4);
  float* pd      = (float*)alloc((size_t)N*4);
  float* invb    = (float*)alloc((size_t)N*4);
  int*   deg     = (int*)  alloc((size_t)N*4);
  int*   offs    = (int*)  alloc((size_t)(N+1)*4);
  int*   cursor  = (int*)  alloc((size_t)N*4);
  int*   pos     = (int*)  alloc((size_t)E*4);
  int*   src_csr = (int*)  alloc((size_t)E*4);
  int*   dst_csr = (int*)  alloc((size_t)E*4);
  float* qcsr    = (float*)alloc((size_t)3*E*4);
  float* lgits   = (float*)alloc((size_t)E*4);
  float* wbuf    = (float*)alloc((size_t)E*4);
  int*   bsum    = (int*)  alloc((size_t)1024*4);
  int*   bbase   = (int*)  alloc((size_t)1024*4);
  float* hg      = (float*)alloc((size_t)3*NG*HD*4);
  float* cnt     = (float*)alloc((size_t)NG*4);
  (void)ws_size; (void)n_in; (void)out_size;

  int ethreads = 256;
  int eblocks = (E + ethreads - 1) / ethreads;
  int nwblocks = (N + 3) / 4;
  int nb = (N + 255) / 256;

  hipMemsetAsync(deg, 0, (size_t)N*4, stream);
  hipMemsetAsync(hg, 0, (size_t)3*NG*HD*4, stream);
  k_hist<<<eblocks, ethreads, 0, stream>>>(dst, deg, E);
  k_bsum<<<nb, 64, 0, stream>>>(deg, bsum, N);
  k_bscan<<<1, 1024, 0, stream>>>(bsum, bbase, offs, N, nb);
  k_bprop<<<nb, 256, 0, stream>>>(deg, bbase, offs, cursor, N);
  k_scatter<<<eblocks, ethreads, 0, stream>>>(src, dst, cursor, pos, src_csr, dst_csr, E);
  k_eq<<<eblocks, ethreads, 0, stream>>>(efeat, a1+2*HD, a2+2*HD, a3+2*HD, pos, qcsr, E);
  k_cast<<<(N*16 + 255)/256, 256, 0, stream>>>(x, Xc, N);
  k_wswiz<<<24, 256, 0, stream>>>(W1, W2, W3, Wball);
  k_cnt<<<1, 64, 0, stream>>>(gid, cnt, N);

  const float* as[3] = {a1, a2, a3};
  for(int layer=0; layer<3; layer++){
    const unsigned* Ac = (layer==0) ? Xc : Hc;
    k_gemm_mfma<<<(N+127)/128, 256, 0, stream>>>(Ac, Wball + (size_t)layer*2048*8,
                                                 (unsigned short*)Zc, as[layer], ps, pd, N);
    k_logits<<<eblocks, ethreads, 0, stream>>>(ps, pd, src_csr, dst_csr,
                                               qcsr + (size_t)layer*E, lgits, E);
    k_soft<<<nwblocks, 256, 0, stream>>>(lgits, offs, wbuf, invb, N);
    for(int c=0; c<4; c++)
      k_aggc<<<nwblocks, 256, 0, stream>>>(Zc, wbuf, offs, src_csr, invb, Hc, N, c);
    k_readout<<<NG*RCH, 64, 0, stream>>>(Hc, gid, watt, batt, hg + (size_t)layer*NG*HD, N);
  }
  k_final<<<1, 256, 0, stream>>>(hg, cnt, Wc, bc, out);
}

// Round 6
// 567.418 us; speedup vs baseline: 1.6015x; 1.6015x over previous
//
#include <hip/hip_runtime.h>
#include <math.h>

#define HD 128      // hidden dim (= F_IN)
#define ED 16       // edge feat dim
#define NG 64       // num graphs
#define NC 10       // num classes

typedef short bf16x8 __attribute__((ext_vector_type(8)));
typedef float f32x4 __attribute__((ext_vector_type(4)));

__device__ __forceinline__ unsigned short f2b(float x){
  unsigned u = __float_as_uint(x);
  unsigned r = (u + 0x7fffu + ((u >> 16) & 1u)) >> 16;
  return (unsigned short)r;
}
__device__ __forceinline__ float blo(unsigned p){ return __uint_as_float(p << 16); }
__device__ __forceinline__ float bhi(unsigned p){ return __uint_as_float(p & 0xffff0000u); }

// ---------------- CSR build ----------------
__global__ void k_hist(const int* __restrict__ dst, int* __restrict__ deg, int E){
  int e = blockIdx.x*blockDim.x + threadIdx.x;
  if(e<E) atomicAdd(&deg[dst[e]], 1);
}

__global__ __launch_bounds__(64) void k_bsum(const int* __restrict__ deg, int* __restrict__ bsum, int N){
  int b = blockIdx.x, t = threadIdx.x;
  int i = b*256 + t*4;
  int s = 0;
  if(i+3 < N){ int4 v = *(const int4*)&deg[i]; s = v.x+v.y+v.z+v.w; }
  else { for(int k=0;k<4;k++) if(i+k<N) s += deg[i+k]; }
  #pragma unroll
  for(int o=32;o;o>>=1) s += __shfl_xor(s,o);
  if(t==0) bsum[b] = s;
}

__global__ __launch_bounds__(1024) void k_bscan(const int* __restrict__ bsum, int* __restrict__ bbase,
                                                int* __restrict__ offs, int N, int nb){
  __shared__ int sh[1024];
  int t = threadIdx.x;
  int v = (t < nb) ? bsum[t] : 0;
  sh[t] = v; __syncthreads();
  for(int o=1;o<1024;o<<=1){ int u = (t>=o)?sh[t-o]:0; __syncthreads(); sh[t]+=u; __syncthreads(); }
  if(t < nb) bbase[t] = sh[t] - v;
  if(t == 1023) offs[N] = sh[1023];
}

__global__ __launch_bounds__(256) void k_bprop(const int* __restrict__ deg, const int* __restrict__ bbase,
                                               int* __restrict__ offs, int* __restrict__ cursor, int N){
  __shared__ int sh[256];
  int b = blockIdx.x, t = threadIdx.x;
  int i = b*256 + t;
  int v = (i<N) ? deg[i] : 0;
  sh[t] = v; __syncthreads();
  for(int o=1;o<256;o<<=1){ int u = (t>=o)?sh[t-o]:0; __syncthreads(); sh[t]+=u; __syncthreads(); }
  if(i<N){ int o_ = bbase[b] + sh[t] - v; offs[i] = o_; cursor[i] = o_; }
}

// ---------------- scatter + fused edge-feature dots: one 32B record per edge ----------------
// rec[p] (8 uints): [src, dst, q1, q2, q3, pad, pad, pad]
__global__ void k_scatterq(const int* __restrict__ src, const int* __restrict__ dst,
                           const float* __restrict__ ef,
                           const float* __restrict__ a1e, const float* __restrict__ a2e,
                           const float* __restrict__ a3e,
                           int* __restrict__ cursor, unsigned* __restrict__ rec, int E){
  int e = blockIdx.x*blockDim.x + threadIdx.x;
  if(e>=E) return;
  const float* f = &ef[(size_t)e*ED];
  float q1=0.f, q2=0.f, q3=0.f;
  #pragma unroll
  for(int i=0;i<ED;i++){
    float fv = f[i];
    q1 = fmaf(fv, a1e[i], q1);
    q2 = fmaf(fv, a2e[i], q2);
    q3 = fmaf(fv, a3e[i], q3);
  }
  int d = dst[e];
  int p = atomicAdd(&cursor[d], 1);
  uint4 A; A.x = (unsigned)src[e]; A.y = (unsigned)d;
  A.z = __float_as_uint(q1); A.w = __float_as_uint(q2);
  uint4 B; B.x = __float_as_uint(q3); B.y = 0u; B.z = 0u; B.w = 0u;
  *(uint4*)&rec[(size_t)p*8]     = A;
  *(uint4*)&rec[(size_t)p*8 + 4] = B;
}

// ---------------- fp32 -> bf16 cast, row-major ----------------
__global__ void k_cast(const float* __restrict__ x, unsigned short* __restrict__ xb, int n){
  int i = (blockIdx.x*blockDim.x + threadIdx.x)*8;
  if(i >= n) return;
  float4 v0 = *(const float4*)&x[i];
  float4 v1 = *(const float4*)&x[i+4];
  uint4 o;
  o.x = f2b(v0.x) | ((unsigned)f2b(v0.y)<<16);
  o.y = f2b(v0.z) | ((unsigned)f2b(v0.w)<<16);
  o.z = f2b(v1.x) | ((unsigned)f2b(v1.y)<<16);
  o.w = f2b(v1.z) | ((unsigned)f2b(v1.w)<<16);
  *(uint4*)&xb[i] = o;
}

// ---------------- W -> B-fragment-swizzled bf16 (all 3 layers) ----------------
__global__ __launch_bounds__(256) void k_wswiz(const float* __restrict__ W1, const float* __restrict__ W2,
                        const float* __restrict__ W3, unsigned short* __restrict__ Wb){
  int idx = blockIdx.x*256 + threadIdx.x;    // 3 * 2048
  if(idx >= 3*2048) return;
  int layer = idx >> 11;
  int r = idx & 2047;
  const float* W = (layer==0)?W1:((layer==1)?W2:W3);
  int lane = r & 63, tile = r >> 6;
  int kt = tile >> 3, nt = tile & 7;
  int qq = lane >> 4, cc = lane & 15;
  int kbase = kt*32 + qq*8;
  int col = nt*16 + cc;
  unsigned short tmp[8];
  #pragma unroll
  for(int j=0;j<8;j++) tmp[j] = f2b(W[(size_t)(kbase+j)*HD + col]);
  uint4 o;
  o.x = tmp[0]|((unsigned)tmp[1]<<16); o.y = tmp[2]|((unsigned)tmp[3]<<16);
  o.z = tmp[4]|((unsigned)tmp[5]<<16); o.w = tmp[6]|((unsigned)tmp[7]<<16);
  *(uint4*)&Wb[(size_t)idx*8] = o;
}

// ---------------- MFMA GEMM: Zb[M x 128](bf16) = Ab @ W, fused pdots ----------------
__global__ __launch_bounds__(256) void k_gemm_mfma(
    const unsigned short* __restrict__ Ab,   // M x 128 bf16 row-major
    const unsigned short* __restrict__ Wb,   // swizzled B-frags
    unsigned short* __restrict__ Zb,         // M x 128 bf16 out
    const float* __restrict__ avec,          // [a_src(128) | a_dst(128) | a_e(16)]
    float* __restrict__ ps, float* __restrict__ pd, int M)
{
  int tid = threadIdx.x;
  int w = tid >> 6, lane = tid & 63;
  int q = lane >> 4, c = lane & 15;
  int rowbase = blockIdx.x*128 + w*32;
  f32x4 acc[2][8];
  #pragma unroll
  for(int t=0;t<2;t++)
    #pragma unroll
    for(int n=0;n<8;n++) acc[t][n] = (f32x4){0.f,0.f,0.f,0.f};

  int r0 = rowbase + c;      if(r0 > M-1) r0 = M-1;
  int r1 = rowbase + 16 + c; if(r1 > M-1) r1 = M-1;
  #pragma unroll
  for(int kt=0; kt<4; kt++){
    int ko = kt*32 + q*8;
    bf16x8 a0 = __builtin_bit_cast(bf16x8, *(const uint4*)&Ab[(size_t)r0*HD + ko]);
    bf16x8 a1 = __builtin_bit_cast(bf16x8, *(const uint4*)&Ab[(size_t)r1*HD + ko]);
    #pragma unroll
    for(int n=0;n<8;n++){
      bf16x8 b = __builtin_bit_cast(bf16x8, *(const uint4*)&Wb[(((size_t)(kt*8+n))*64 + lane)*8]);
      acc[0][n] = __builtin_amdgcn_mfma_f32_16x16x32_bf16(a0, b, acc[0][n], 0,0,0);
      acc[1][n] = __builtin_amdgcn_mfma_f32_16x16x32_bf16(a1, b, acc[1][n], 0,0,0);
    }
  }
  float asv[8], adv[8];
  #pragma unroll
  for(int n=0;n<8;n++){ asv[n] = avec[n*16+c]; adv[n] = avec[HD + n*16+c]; }
  #pragma unroll
  for(int t=0;t<2;t++){
    #pragma unroll
    for(int r=0;r<4;r++){
      int grow = rowbase + t*16 + 4*q + r;
      bool ok = grow < M;
      #pragma unroll
      for(int n=0;n<8;n++){
        if(ok) Zb[(size_t)grow*HD + n*16 + c] = f2b(acc[t][n][r]);
      }
      float pp = 0.f, dd = 0.f;
      #pragma unroll
      for(int n=0;n<8;n++){ pp = fmaf(acc[t][n][r], asv[n], pp); dd = fmaf(acc[t][n][r], adv[n], dd); }
      #pragma unroll
      for(int o=1;o<16;o<<=1){ pp += __shfl_xor(pp,o); dd += __shfl_xor(dd,o); }
      if(ok && c==0){ ps[grow] = pp; pd[grow] = dd; }
    }
  }
}

// ---------------- fused logits + softmax + aggregate + relu + h(bf16) + att ----------------
// node-parallel (wave per node), quad-parallel over edges; no max-subtraction
// (logits are O(±10): exp is safe in fp32, ratios are identical).
__global__ __launch_bounds__(256) void k_agg2(const uint4* __restrict__ zb4,  // z rows: 16 uint4/node
                                              const int* __restrict__ offs,
                                              const unsigned* __restrict__ rec, // 8 uints/edge CSR
                                              const float* __restrict__ ps,
                                              const float* __restrict__ pd,
                                              int layer,
                                              unsigned* __restrict__ hbu,     // h bf16 row-major
                                              float* __restrict__ att,
                                              const float* __restrict__ watt,
                                              const float* __restrict__ batt, int N){
  int wid = blockIdx.x*4 + (threadIdx.x>>6);
  int lane = threadIdx.x & 63;
  if(wid >= N) return;
  int q = lane >> 4, c = lane & 15;
  int d0 = offs[wid], d1 = offs[wid+1];
  float pdv = pd[wid];
  float acc[8];
  #pragma unroll
  for(int i=0;i<8;i++) acc[i]=0.f;
  float ssum = 0.f;
  for(int j=d0; j<d1; j+=4){
    int jq = j + q;
    bool v = jq < d1;
    int e = v ? jq : (d1-1);
    const unsigned* r = &rec[(size_t)e*8];
    int u = (int)r[0];
    float ql = __uint_as_float(r[2+layer]);
    float l = ps[u] + pdv + ql;
    l = (l >= 0.f) ? l : 0.2f*l;
    float wgt = v ? __expf(l) : 0.f;
    uint4 P = zb4[(size_t)u*16 + c];
    ssum += wgt;
    acc[0] = fmaf(wgt, blo(P.x), acc[0]); acc[1] = fmaf(wgt, bhi(P.x), acc[1]);
    acc[2] = fmaf(wgt, blo(P.y), acc[2]); acc[3] = fmaf(wgt, bhi(P.y), acc[3]);
    acc[4] = fmaf(wgt, blo(P.z), acc[4]); acc[5] = fmaf(wgt, bhi(P.z), acc[5]);
    acc[6] = fmaf(wgt, blo(P.w), acc[6]); acc[7] = fmaf(wgt, bhi(P.w), acc[7]);
  }
  #pragma unroll
  for(int i=0;i<8;i++){ acc[i] += __shfl_xor(acc[i],16); acc[i] += __shfl_xor(acc[i],32); }
  ssum += __shfl_xor(ssum,16); ssum += __shfl_xor(ssum,32);
  float inv = (d1 > d0) ? 1.0f/ssum : 0.0f;
  #pragma unroll
  for(int i=0;i<8;i++) acc[i] = fmaxf(acc[i]*inv, 0.f);   // normalize + relu
  hbu[(size_t)wid*64 + c*4 + q] = (unsigned)f2b(acc[2*q]) | ((unsigned)f2b(acc[2*q+1])<<16);
  // readout attention scalar (lanes with same q hold cols c*8..c*8+7)
  float4 w0 = *(const float4*)&watt[c*8];
  float4 w1 = *(const float4*)&watt[c*8+4];
  float t = acc[0]*w0.x + acc[1]*w0.y + acc[2]*w0.z + acc[3]*w0.w
          + acc[4]*w1.x + acc[5]*w1.y + acc[6]*w1.z + acc[7]*w1.w;
  #pragma unroll
  for(int o=1;o<16;o<<=1) t += __shfl_xor(t,o);
  t += batt[0];
  float lr = (t >= 0.f) ? t : 0.01f*t;
  if(lane==0) att[wid] = __expf(lr);
}

// ---------------- readout: hg[g] += att[v] * h[v]  (bf16 h, precomputed att) ----------------
#define RCH 8
__global__ __launch_bounds__(64) void k_readout(const unsigned* __restrict__ hbu,
                                                const float* __restrict__ att,
                                                const int* __restrict__ gid,
                                                float* __restrict__ hg, int N){
  int g = blockIdx.x / RCH;
  int chunk = blockIdx.x % RCH;
  int t = threadIdx.x;   // 64: thread owns cols 2t, 2t+1
  int lo=0, hi=N;
  while(lo<hi){ int mid=(lo+hi)>>1; if(gid[mid] < g) lo=mid+1; else hi=mid; }
  int start = lo; lo = start; hi = N;
  while(lo<hi){ int mid=(lo+hi)>>1; if(gid[mid] < g+1) lo=mid+1; else hi=mid; }
  int end = lo;
  int len = end - start;
  int c0 = start + (int)(((long long)len * chunk) / RCH);
  int c1 = start + (int)(((long long)len * (chunk+1)) / RCH);
  float acc0 = 0.f, acc1 = 0.f;
  for(int v=c0; v<c1; v++){
    unsigned P = hbu[(size_t)v*64 + t];
    float a = att[v];
    acc0 = fmaf(a, blo(P), acc0);
    acc1 = fmaf(a, bhi(P), acc1);
  }
  atomicAdd(&hg[g*HD + 2*t],     acc0);
  atomicAdd(&hg[g*HD + 2*t + 1], acc1);
}

// ---------------- per-graph node counts ----------------
__global__ __launch_bounds__(64) void k_cnt(const int* __restrict__ gid, float* __restrict__ cnt, int N){
  int g = threadIdx.x;
  if(g >= NG) return;
  int lo=0, hi=N;
  while(lo<hi){ int mid=(lo+hi)>>1; if(gid[mid] < g) lo=mid+1; else hi=mid; }
  int start = lo; lo = start; hi = N;
  while(lo<hi){ int mid=(lo+hi)>>1; if(gid[mid] < g+1) lo=mid+1; else hi=mid; }
  cnt[g] = (float)(lo - start);
}

// ---------------- final classifier + log_softmax ----------------
__global__ __launch_bounds__(256) void k_final(const float* __restrict__ hg,
                                               const float* __restrict__ cnt,
                                               const float* __restrict__ Wc,
                                               const float* __restrict__ bc,
                                               float* __restrict__ out){
  __shared__ float y[NG][NC];
  int tid = threadIdx.x;
  for(int idx=tid; idx<NG*NC; idx+=256){
    int g = idx / NC, c = idx % NC;
    float invc = 1.f / fmaxf(cnt[g], 1.f);
    float s = bc[c];
    #pragma unroll
    for(int part=0; part<3; part++){
      const float* row = &hg[part*NG*HD + g*HD];
      for(int f=0; f<HD; f++) s = fmaf(row[f]*invc, Wc[(part*HD+f)*NC + c], s);
    }
    y[g][c] = s;
  }
  __syncthreads();
  if(tid < NG){
    float mx = -INFINITY;
    #pragma unroll
    for(int c=0;c<NC;c++) mx = fmaxf(mx, y[tid][c]);
    float s = 0.f;
    #pragma unroll
    for(int c=0;c<NC;c++) s += __expf(y[tid][c] - mx);
    float ls = logf(s);
    #pragma unroll
    for(int c=0;c<NC;c++) out[tid*NC + c] = y[tid][c] - mx - ls;
  }
}

// ---------------- host ----------------
extern "C" void kernel_launch(void* const* d_in, const int* in_sizes, int n_in,
                              void* d_out, int out_size, void* d_ws, size_t ws_size,
                              hipStream_t stream) {
  const float* x     = (const float*)d_in[0];
  const float* efeat = (const float*)d_in[1];
  const int*   src   = (const int*)d_in[2];
  const int*   dst   = (const int*)d_in[3];
  const int*   gid   = (const int*)d_in[4];
  const float* W1    = (const float*)d_in[5];
  const float* a1    = (const float*)d_in[6];
  const float* W2    = (const float*)d_in[7];
  const float* a2    = (const float*)d_in[8];
  const float* W3    = (const float*)d_in[9];
  const float* a3    = (const float*)d_in[10];
  const float* watt  = (const float*)d_in[11];
  const float* batt  = (const float*)d_in[12];
  const float* Wc    = (const float*)d_in[13];
  const float* bc    = (const float*)d_in[14];
  float* out = (float*)d_out;

  int N = in_sizes[4];
  int E = in_sizes[2];

  char* p = (char*)d_ws;
  auto alloc = [&](size_t bytes)->void*{
    void* r = (void*)p;
    p += (bytes + 255) & ~(size_t)255;
    return r;
  };
  unsigned short* Xb = (unsigned short*)alloc((size_t)N*HD*2);  // x bf16 row-major
  unsigned short* Hb = (unsigned short*)alloc((size_t)N*HD*2);  // h bf16
  unsigned short* Zb = (unsigned short*)alloc((size_t)N*HD*2);  // z bf16
  unsigned short* Wball = (unsigned short*)alloc((size_t)3*2048*8*2);
  float* ps      = (float*)alloc((size_t)N*4);
  float* pd      = (float*)alloc((size_t)N*4);
  float* att     = (float*)alloc((size_t)N*4);
  int*   deg     = (int*)  alloc((size_t)N*4);
  int*   offs    = (int*)  alloc((size_t)(N+1)*4);
  int*   cursor  = (int*)  alloc((size_t)N*4);
  unsigned* rec  = (unsigned*)alloc((size_t)E*8*4);   // 32B per edge
  int*   bsum    = (int*)  alloc((size_t)1024*4);
  int*   bbase   = (int*)  alloc((size_t)1024*4);
  float* hg      = (float*)alloc((size_t)3*NG*HD*4);
  float* cnt     = (float*)alloc((size_t)NG*4);
  (void)ws_size; (void)n_in; (void)out_size;

  int ethreads = 256;
  int eblocks = (E + ethreads - 1) / ethreads;
  int nwblocks = (N + 3) / 4;
  int nb = (N + 255) / 256;

  hipMemsetAsync(deg, 0, (size_t)N*4, stream);
  hipMemsetAsync(hg, 0, (size_t)3*NG*HD*4, stream);
  k_hist<<<eblocks, ethreads, 0, stream>>>(dst, deg, E);
  k_bsum<<<nb, 64, 0, stream>>>(deg, bsum, N);
  k_bscan<<<1, 1024, 0, stream>>>(bsum, bbase, offs, N, nb);
  k_bprop<<<nb, 256, 0, stream>>>(deg, bbase, offs, cursor, N);
  k_scatterq<<<eblocks, ethreads, 0, stream>>>(src, dst, efeat, a1+2*HD, a2+2*HD, a3+2*HD,
                                               cursor, rec, E);
  k_cast<<<((N*HD/8) + 255)/256, 256, 0, stream>>>(x, Xb, N*HD);
  k_wswiz<<<24, 256, 0, stream>>>(W1, W2, W3, Wball);
  k_cnt<<<1, 64, 0, stream>>>(gid, cnt, N);

  const float* as[3] = {a1, a2, a3};
  for(int layer=0; layer<3; layer++){
    const unsigned short* Ab = (layer==0) ? Xb : Hb;
    k_gemm_mfma<<<(N+127)/128, 256, 0, stream>>>(Ab, Wball + (size_t)layer*2048*8, Zb,
                                                 as[layer], ps, pd, N);
    k_agg2<<<nwblocks, 256, 0, stream>>>((const uint4*)Zb, offs, rec, ps, pd, layer,
                                         (unsigned*)Hb, att, watt, batt, N);
    k_readout<<<NG*RCH, 64, 0, stream>>>((const unsigned*)Hb, att, gid,
                                         hg + (size_t)layer*NG*HD, N);
  }
  k_final<<<1, 256, 0, stream>>>(hg, cnt, Wc, bc, out);
}

// Round 7
// 528.700 us; speedup vs baseline: 1.7188x; 1.0732x over previous
//
#include <hip/hip_runtime.h>
#include <math.h>

#define HD 128      // hidden dim (= F_IN)
#define ED 16       // edge feat dim
#define NG 64       // num graphs
#define NC 10       // num classes

typedef short bf16x8 __attribute__((ext_vector_type(8)));
typedef float f32x4 __attribute__((ext_vector_type(4)));

__device__ __forceinline__ unsigned short f2b(float x){
  unsigned u = __float_as_uint(x);
  unsigned r = (u + 0x7fffu + ((u >> 16) & 1u)) >> 16;
  return (unsigned short)r;
}
__device__ __forceinline__ float blo(unsigned p){ return __uint_as_float(p << 16); }
__device__ __forceinline__ float bhi(unsigned p){ return __uint_as_float(p & 0xffff0000u); }

// ---------------- CSR build ----------------
__global__ void k_hist(const int* __restrict__ dst, int* __restrict__ deg, int E){
  int e4 = (blockIdx.x*blockDim.x + threadIdx.x)*4;
  if(e4+3 < E){
    int4 d = *(const int4*)&dst[e4];
    atomicAdd(&deg[d.x], 1); atomicAdd(&deg[d.y], 1);
    atomicAdd(&deg[d.z], 1); atomicAdd(&deg[d.w], 1);
  } else {
    for(int k=0;k<4;k++) if(e4+k<E) atomicAdd(&deg[dst[e4+k]], 1);
  }
}

__global__ __launch_bounds__(64) void k_bsum(const int* __restrict__ deg, int* __restrict__ bsum, int N){
  int b = blockIdx.x, t = threadIdx.x;
  int i = b*256 + t*4;
  int s = 0;
  if(i+3 < N){ int4 v = *(const int4*)&deg[i]; s = v.x+v.y+v.z+v.w; }
  else { for(int k=0;k<4;k++) if(i+k<N) s += deg[i+k]; }
  #pragma unroll
  for(int o=32;o;o>>=1) s += __shfl_xor(s,o);
  if(t==0) bsum[b] = s;
}

__global__ __launch_bounds__(1024) void k_bscan(const int* __restrict__ bsum, int* __restrict__ bbase,
                                                int* __restrict__ offs, int N, int nb){
  __shared__ int sh[1024];
  int t = threadIdx.x;
  int v = (t < nb) ? bsum[t] : 0;
  sh[t] = v; __syncthreads();
  for(int o=1;o<1024;o<<=1){ int u = (t>=o)?sh[t-o]:0; __syncthreads(); sh[t]+=u; __syncthreads(); }
  if(t < nb) bbase[t] = sh[t] - v;
  if(t == 1023) offs[N] = sh[1023];
}

__global__ __launch_bounds__(256) void k_bprop(const int* __restrict__ deg, const int* __restrict__ bbase,
                                               int* __restrict__ offs, int* __restrict__ cursor, int N){
  __shared__ int sh[256];
  int b = blockIdx.x, t = threadIdx.x;
  int i = b*256 + t;
  int v = (i<N) ? deg[i] : 0;
  sh[t] = v; __syncthreads();
  for(int o=1;o<256;o<<=1){ int u = (t>=o)?sh[t-o]:0; __syncthreads(); sh[t]+=u; __syncthreads(); }
  if(i<N){ int o_ = bbase[b] + sh[t] - v; offs[i] = o_; cursor[i] = o_; }
}

// ---------------- scatter + fused edge dots: ONE 16B record per edge ----------------
// rec[p] (uint4): {src, q1, q2, q3}   (dst not needed downstream)
__global__ void k_scatterq(const int* __restrict__ src, const int* __restrict__ dst,
                           const float* __restrict__ ef,
                           const float* __restrict__ a1e, const float* __restrict__ a2e,
                           const float* __restrict__ a3e,
                           int* __restrict__ cursor, uint4* __restrict__ rec, int E){
  int e = blockIdx.x*blockDim.x + threadIdx.x;
  if(e>=E) return;
  const float* f = &ef[(size_t)e*ED];
  float q1=0.f, q2=0.f, q3=0.f;
  #pragma unroll
  for(int i=0;i<ED;i++){
    float fv = f[i];
    q1 = fmaf(fv, a1e[i], q1);
    q2 = fmaf(fv, a2e[i], q2);
    q3 = fmaf(fv, a3e[i], q3);
  }
  int d = dst[e];
  int p = atomicAdd(&cursor[d], 1);
  uint4 A;
  A.x = (unsigned)src[e];
  A.y = __float_as_uint(q1);
  A.z = __float_as_uint(q2);
  A.w = __float_as_uint(q3);
  rec[p] = A;
}

// ---------------- fp32 -> bf16 cast, row-major ----------------
__global__ void k_cast(const float* __restrict__ x, unsigned short* __restrict__ xb, int n){
  int i = (blockIdx.x*blockDim.x + threadIdx.x)*8;
  if(i >= n) return;
  float4 v0 = *(const float4*)&x[i];
  float4 v1 = *(const float4*)&x[i+4];
  uint4 o;
  o.x = f2b(v0.x) | ((unsigned)f2b(v0.y)<<16);
  o.y = f2b(v0.z) | ((unsigned)f2b(v0.w)<<16);
  o.z = f2b(v1.x) | ((unsigned)f2b(v1.y)<<16);
  o.w = f2b(v1.z) | ((unsigned)f2b(v1.w)<<16);
  *(uint4*)&xb[i] = o;
}

// ---------------- W -> B-fragment-swizzled bf16 (all 3 layers) ----------------
__global__ __launch_bounds__(256) void k_wswiz(const float* __restrict__ W1, const float* __restrict__ W2,
                        const float* __restrict__ W3, unsigned short* __restrict__ Wb){
  int idx = blockIdx.x*256 + threadIdx.x;    // 3 * 2048
  if(idx >= 3*2048) return;
  int layer = idx >> 11;
  int r = idx & 2047;
  const float* W = (layer==0)?W1:((layer==1)?W2:W3);
  int lane = r & 63, tile = r >> 6;
  int kt = tile >> 3, nt = tile & 7;
  int qq = lane >> 4, cc = lane & 15;
  int kbase = kt*32 + qq*8;
  int col = nt*16 + cc;
  unsigned short tmp[8];
  #pragma unroll
  for(int j=0;j<8;j++) tmp[j] = f2b(W[(size_t)(kbase+j)*HD + col]);
  uint4 o;
  o.x = tmp[0]|((unsigned)tmp[1]<<16); o.y = tmp[2]|((unsigned)tmp[3]<<16);
  o.z = tmp[4]|((unsigned)tmp[5]<<16); o.w = tmp[6]|((unsigned)tmp[7]<<16);
  *(uint4*)&Wb[(size_t)idx*8] = o;
}

// ---------------- MFMA GEMM: Zb[M x 128](bf16) = Ab @ W, fused pdots ----------------
__global__ __launch_bounds__(256) void k_gemm_mfma(
    const unsigned short* __restrict__ Ab,
    const unsigned short* __restrict__ Wb,
    unsigned short* __restrict__ Zb,
    const float* __restrict__ avec,
    float* __restrict__ ps, float* __restrict__ pd, int M)
{
  int tid = threadIdx.x;
  int w = tid >> 6, lane = tid & 63;
  int q = lane >> 4, c = lane & 15;
  int rowbase = blockIdx.x*128 + w*32;
  f32x4 acc[2][8];
  #pragma unroll
  for(int t=0;t<2;t++)
    #pragma unroll
    for(int n=0;n<8;n++) acc[t][n] = (f32x4){0.f,0.f,0.f,0.f};

  int r0 = rowbase + c;      if(r0 > M-1) r0 = M-1;
  int r1 = rowbase + 16 + c; if(r1 > M-1) r1 = M-1;
  #pragma unroll
  for(int kt=0; kt<4; kt++){
    int ko = kt*32 + q*8;
    bf16x8 a0 = __builtin_bit_cast(bf16x8, *(const uint4*)&Ab[(size_t)r0*HD + ko]);
    bf16x8 a1 = __builtin_bit_cast(bf16x8, *(const uint4*)&Ab[(size_t)r1*HD + ko]);
    #pragma unroll
    for(int n=0;n<8;n++){
      bf16x8 b = __builtin_bit_cast(bf16x8, *(const uint4*)&Wb[(((size_t)(kt*8+n))*64 + lane)*8]);
      acc[0][n] = __builtin_amdgcn_mfma_f32_16x16x32_bf16(a0, b, acc[0][n], 0,0,0);
      acc[1][n] = __builtin_amdgcn_mfma_f32_16x16x32_bf16(a1, b, acc[1][n], 0,0,0);
    }
  }
  float asv[8], adv[8];
  #pragma unroll
  for(int n=0;n<8;n++){ asv[n] = avec[n*16+c]; adv[n] = avec[HD + n*16+c]; }
  #pragma unroll
  for(int t=0;t<2;t++){
    #pragma unroll
    for(int r=0;r<4;r++){
      int grow = rowbase + t*16 + 4*q + r;
      bool ok = grow < M;
      #pragma unroll
      for(int n=0;n<8;n++){
        if(ok) Zb[(size_t)grow*HD + n*16 + c] = f2b(acc[t][n][r]);
      }
      float pp = 0.f, dd = 0.f;
      #pragma unroll
      for(int n=0;n<8;n++){ pp = fmaf(acc[t][n][r], asv[n], pp); dd = fmaf(acc[t][n][r], adv[n], dd); }
      #pragma unroll
      for(int o=1;o<16;o<<=1){ pp += __shfl_xor(pp,o); dd += __shfl_xor(dd,o); }
      if(ok && c==0){ ps[grow] = pp; pd[grow] = dd; }
    }
  }
}

// ---------------- fused logits + softmax + aggregate + relu + h(bf16) + att ----------------
__global__ __launch_bounds__(256) void k_agg2(const uint4* __restrict__ zb4,
                                              const int* __restrict__ offs,
                                              const uint4* __restrict__ rec,  // 16B/edge CSR
                                              const float* __restrict__ ps,
                                              const float* __restrict__ pd,
                                              int layer,
                                              unsigned* __restrict__ hbu,
                                              float* __restrict__ att,
                                              const float* __restrict__ watt,
                                              const float* __restrict__ batt, int N){
  int wid = blockIdx.x*4 + (threadIdx.x>>6);
  int lane = threadIdx.x & 63;
  if(wid >= N) return;
  int q = lane >> 4, c = lane & 15;
  int d0 = offs[wid], d1 = offs[wid+1];
  float pdv = pd[wid];
  float acc[8];
  #pragma unroll
  for(int i=0;i<8;i++) acc[i]=0.f;
  float ssum = 0.f;
  for(int j=d0; j<d1; j+=4){
    int jq = j + q;
    bool v = jq < d1;
    int e = v ? jq : (d1-1);
    uint4 R = rec[e];
    int u = (int)R.x;
    float ql = __uint_as_float(layer==0 ? R.y : (layer==1 ? R.z : R.w));
    float l = ps[u] + pdv + ql;
    l = (l >= 0.f) ? l : 0.2f*l;
    float wgt = v ? __expf(l) : 0.f;
    uint4 P = zb4[(size_t)u*16 + c];
    ssum += wgt;
    acc[0] = fmaf(wgt, blo(P.x), acc[0]); acc[1] = fmaf(wgt, bhi(P.x), acc[1]);
    acc[2] = fmaf(wgt, blo(P.y), acc[2]); acc[3] = fmaf(wgt, bhi(P.y), acc[3]);
    acc[4] = fmaf(wgt, blo(P.z), acc[4]); acc[5] = fmaf(wgt, bhi(P.z), acc[5]);
    acc[6] = fmaf(wgt, blo(P.w), acc[6]); acc[7] = fmaf(wgt, bhi(P.w), acc[7]);
  }
  #pragma unroll
  for(int i=0;i<8;i++){ acc[i] += __shfl_xor(acc[i],16); acc[i] += __shfl_xor(acc[i],32); }
  ssum += __shfl_xor(ssum,16); ssum += __shfl_xor(ssum,32);
  float inv = (d1 > d0) ? 1.0f/ssum : 0.0f;
  #pragma unroll
  for(int i=0;i<8;i++) acc[i] = fmaxf(acc[i]*inv, 0.f);
  hbu[(size_t)wid*64 + c*4 + q] = (unsigned)f2b(acc[2*q]) | ((unsigned)f2b(acc[2*q+1])<<16);
  float4 w0 = *(const float4*)&watt[c*8];
  float4 w1 = *(const float4*)&watt[c*8+4];
  float t = acc[0]*w0.x + acc[1]*w0.y + acc[2]*w0.z + acc[3]*w0.w
          + acc[4]*w1.x + acc[5]*w1.y + acc[6]*w1.z + acc[7]*w1.w;
  #pragma unroll
  for(int o=1;o<16;o<<=1) t += __shfl_xor(t,o);
  t += batt[0];
  float lr = (t >= 0.f) ? t : 0.01f*t;
  if(lane==0) att[wid] = __expf(lr);
}

// ---------------- readout: hg[g] += att[v] * h[v] ----------------
#define RCH 8
__global__ __launch_bounds__(64) void k_readout(const unsigned* __restrict__ hbu,
                                                const float* __restrict__ att,
                                                const int* __restrict__ gid,
                                                float* __restrict__ hg, int N){
  int g = blockIdx.x / RCH;
  int chunk = blockIdx.x % RCH;
  int t = threadIdx.x;
  int lo=0, hi=N;
  while(lo<hi){ int mid=(lo+hi)>>1; if(gid[mid] < g) lo=mid+1; else hi=mid; }
  int start = lo; lo = start; hi = N;
  while(lo<hi){ int mid=(lo+hi)>>1; if(gid[mid] < g+1) lo=mid+1; else hi=mid; }
  int end = lo;
  int len = end - start;
  int c0 = start + (int)(((long long)len * chunk) / RCH);
  int c1 = start + (int)(((long long)len * (chunk+1)) / RCH);
  float acc0 = 0.f, acc1 = 0.f;
  for(int v=c0; v<c1; v++){
    unsigned P = hbu[(size_t)v*64 + t];
    float a = att[v];
    acc0 = fmaf(a, blo(P), acc0);
    acc1 = fmaf(a, bhi(P), acc1);
  }
  atomicAdd(&hg[g*HD + 2*t],     acc0);
  atomicAdd(&hg[g*HD + 2*t + 1], acc1);
}

// ---------------- per-graph node counts ----------------
__global__ __launch_bounds__(64) void k_cnt(const int* __restrict__ gid, float* __restrict__ cnt, int N){
  int g = threadIdx.x;
  if(g >= NG) return;
  int lo=0, hi=N;
  while(lo<hi){ int mid=(lo+hi)>>1; if(gid[mid] < g) lo=mid+1; else hi=mid; }
  int start = lo; lo = start; hi = N;
  while(lo<hi){ int mid=(lo+hi)>>1; if(gid[mid] < g+1) lo=mid+1; else hi=mid; }
  cnt[g] = (float)(lo - start);
}

// ---------------- final classifier + log_softmax (parallel: block per graph) ----------------
__global__ __launch_bounds__(384) void k_final(const float* __restrict__ hg,
                                               const float* __restrict__ cnt,
                                               const float* __restrict__ Wc,
                                               const float* __restrict__ bc,
                                               float* __restrict__ out){
  int g = blockIdx.x;
  int t = threadIdx.x;          // 0..383: element t of the concatenated 384-vector
  __shared__ float red[6];
  __shared__ float yv[NC];
  float invc = 1.f / fmaxf(cnt[g], 1.f);
  int part = t >> 7;            // which hg section
  int f = t & 127;
  float v = hg[(size_t)part*NG*HD + g*HD + f] * invc;
  for(int c=0; c<NC; c++){
    float p = v * Wc[(size_t)t*NC + c];
    #pragma unroll
    for(int o=32;o;o>>=1) p += __shfl_xor(p,o);
    if((t&63)==0) red[t>>6] = p;
    __syncthreads();
    if(t==0) yv[c] = bc[c] + red[0]+red[1]+red[2]+red[3]+red[4]+red[5];
    __syncthreads();
  }
  if(t==0){
    float mx = -INFINITY;
    #pragma unroll
    for(int c=0;c<NC;c++) mx = fmaxf(mx, yv[c]);
    float s = 0.f;
    #pragma unroll
    for(int c=0;c<NC;c++) s += __expf(yv[c] - mx);
    float ls = logf(s);
    #pragma unroll
    for(int c=0;c<NC;c++) out[g*NC + c] = yv[c] - mx - ls;
  }
}

// ---------------- host ----------------
extern "C" void kernel_launch(void* const* d_in, const int* in_sizes, int n_in,
                              void* d_out, int out_size, void* d_ws, size_t ws_size,
                              hipStream_t stream) {
  const float* x     = (const float*)d_in[0];
  const float* efeat = (const float*)d_in[1];
  const int*   src   = (const int*)d_in[2];
  const int*   dst   = (const int*)d_in[3];
  const int*   gid   = (const int*)d_in[4];
  const float* W1    = (const float*)d_in[5];
  const float* a1    = (const float*)d_in[6];
  const float* W2    = (const float*)d_in[7];
  const float* a2    = (const float*)d_in[8];
  const float* W3    = (const float*)d_in[9];
  const float* a3    = (const float*)d_in[10];
  const float* watt  = (const float*)d_in[11];
  const float* batt  = (const float*)d_in[12];
  const float* Wc    = (const float*)d_in[13];
  const float* bc    = (const float*)d_in[14];
  float* out = (float*)d_out;

  int N = in_sizes[4];
  int E = in_sizes[2];

  char* p = (char*)d_ws;
  auto alloc = [&](size_t bytes)->void*{
    void* r = (void*)p;
    p += (bytes + 255) & ~(size_t)255;
    return r;
  };
  unsigned short* Xb = (unsigned short*)alloc((size_t)N*HD*2);
  unsigned short* Hb = (unsigned short*)alloc((size_t)N*HD*2);
  unsigned short* Zb = (unsigned short*)alloc((size_t)N*HD*2);
  unsigned short* Wball = (unsigned short*)alloc((size_t)3*2048*8*2);
  float* ps      = (float*)alloc((size_t)N*4);
  float* pd      = (float*)alloc((size_t)N*4);
  float* att     = (float*)alloc((size_t)N*4);
  int*   deg     = (int*)  alloc((size_t)N*4);
  int*   offs    = (int*)  alloc((size_t)(N+1)*4);
  int*   cursor  = (int*)  alloc((size_t)N*4);
  uint4* rec     = (uint4*)alloc((size_t)E*16);   // 16B per edge
  int*   bsum    = (int*)  alloc((size_t)1024*4);
  int*   bbase   = (int*)  alloc((size_t)1024*4);
  float* hg      = (float*)alloc((size_t)3*NG*HD*4);
  float* cnt     = (float*)alloc((size_t)NG*4);
  (void)ws_size; (void)n_in; (void)out_size;

  int ethreads = 256;
  int eblocks = (E + ethreads - 1) / ethreads;
  int nwblocks = (N + 3) / 4;
  int nb = (N + 255) / 256;

  hipMemsetAsync(deg, 0, (size_t)N*4, stream);
  hipMemsetAsync(hg, 0, (size_t)3*NG*HD*4, stream);
  k_hist<<<(E/4 + 255)/256, 256, 0, stream>>>(dst, deg, E);
  k_bsum<<<nb, 64, 0, stream>>>(deg, bsum, N);
  k_bscan<<<1, 1024, 0, stream>>>(bsum, bbase, offs, N, nb);
  k_bprop<<<nb, 256, 0, stream>>>(deg, bbase, offs, cursor, N);
  k_scatterq<<<eblocks, ethreads, 0, stream>>>(src, dst, efeat, a1+2*HD, a2+2*HD, a3+2*HD,
                                               cursor, rec, E);
  k_cast<<<((N*HD/8) + 255)/256, 256, 0, stream>>>(x, Xb, N*HD);
  k_wswiz<<<24, 256, 0, stream>>>(W1, W2, W3, Wball);
  k_cnt<<<1, 64, 0, stream>>>(gid, cnt, N);

  const float* as[3] = {a1, a2, a3};
  for(int layer=0; layer<3; layer++){
    const unsigned short* Ab = (layer==0) ? Xb : Hb;
    k_gemm_mfma<<<(N+127)/128, 256, 0, stream>>>(Ab, Wball + (size_t)layer*2048*8, Zb,
                                                 as[layer], ps, pd, N);
    k_agg2<<<nwblocks, 256, 0, stream>>>((const uint4*)Zb, offs, rec, ps, pd, layer,
                                         (unsigned*)Hb, att, watt, batt, N);
    k_readout<<<NG*RCH, 64, 0, stream>>>((const unsigned*)Hb, att, gid,
                                         hg + (size_t)layer*NG*HD, N);
  }
  k_final<<<NG, 384, 0, stream>>>(hg, cnt, Wc, bc, out);
}

// Round 8
// 488.220 us; speedup vs baseline: 1.8613x; 1.0829x over previous
//
#include <hip/hip_runtime.h>
#include <math.h>

#define HD 128      // hidden dim (= F_IN)
#define ED 16       // edge feat dim
#define NG 64       // num graphs
#define NC 10       // num classes

typedef short bf16x8 __attribute__((ext_vector_type(8)));
typedef float f32x4 __attribute__((ext_vector_type(4)));

__device__ __forceinline__ unsigned short f2b(float x){
  unsigned u = __float_as_uint(x);
  unsigned r = (u + 0x7fffu + ((u >> 16) & 1u)) >> 16;
  return (unsigned short)r;
}
__device__ __forceinline__ float blo(unsigned p){ return __uint_as_float(p << 16); }
__device__ __forceinline__ float bhi(unsigned p){ return __uint_as_float(p & 0xffff0000u); }
__device__ __forceinline__ float bperm_f(int idx, float v){
  return __int_as_float(__builtin_amdgcn_ds_bpermute(idx<<2, __float_as_int(v)));
}
__device__ __forceinline__ int bperm_i(int idx, int v){
  return __builtin_amdgcn_ds_bpermute(idx<<2, v);
}

// ---------------- CSR build ----------------
__global__ void k_hist(const int* __restrict__ dst, int* __restrict__ deg, int E){
  int e4 = (blockIdx.x*blockDim.x + threadIdx.x)*4;
  if(e4+3 < E){
    int4 d = *(const int4*)&dst[e4];
    atomicAdd(&deg[d.x], 1); atomicAdd(&deg[d.y], 1);
    atomicAdd(&deg[d.z], 1); atomicAdd(&deg[d.w], 1);
  } else {
    for(int k=0;k<4;k++) if(e4+k<E) atomicAdd(&deg[dst[e4+k]], 1);
  }
}

__global__ __launch_bounds__(64) void k_bsum(const int* __restrict__ deg, int* __restrict__ bsum, int N){
  int b = blockIdx.x, t = threadIdx.x;
  int i = b*256 + t*4;
  int s = 0;
  if(i+3 < N){ int4 v = *(const int4*)&deg[i]; s = v.x+v.y+v.z+v.w; }
  else { for(int k=0;k<4;k++) if(i+k<N) s += deg[i+k]; }
  #pragma unroll
  for(int o=32;o;o>>=1) s += __shfl_xor(s,o);
  if(t==0) bsum[b] = s;
}

__global__ __launch_bounds__(1024) void k_bscan(const int* __restrict__ bsum, int* __restrict__ bbase,
                                                int* __restrict__ offs, int N, int nb){
  __shared__ int sh[1024];
  int t = threadIdx.x;
  int v = (t < nb) ? bsum[t] : 0;
  sh[t] = v; __syncthreads();
  for(int o=1;o<1024;o<<=1){ int u = (t>=o)?sh[t-o]:0; __syncthreads(); sh[t]+=u; __syncthreads(); }
  if(t < nb) bbase[t] = sh[t] - v;
  if(t == 1023) offs[N] = sh[1023];
}

__global__ __launch_bounds__(256) void k_bprop(const int* __restrict__ deg, const int* __restrict__ bbase,
                                               int* __restrict__ offs, int* __restrict__ cursor, int N){
  __shared__ int sh[256];
  int b = blockIdx.x, t = threadIdx.x;
  int i = b*256 + t;
  int v = (i<N) ? deg[i] : 0;
  sh[t] = v; __syncthreads();
  for(int o=1;o<256;o<<=1){ int u = (t>=o)?sh[t-o]:0; __syncthreads(); sh[t]+=u; __syncthreads(); }
  if(i<N){ int o_ = bbase[b] + sh[t] - v; offs[i] = o_; cursor[i] = o_; }
}

// ---------------- scatter + fused edge dots: ONE 16B record per edge ----------------
// rec[p] (uint4): {src, q1, q2, q3}
__global__ void k_scatterq(const int* __restrict__ src, const int* __restrict__ dst,
                           const float* __restrict__ ef,
                           const float* __restrict__ a1e, const float* __restrict__ a2e,
                           const float* __restrict__ a3e,
                           int* __restrict__ cursor, uint4* __restrict__ rec, int E){
  int e = blockIdx.x*blockDim.x + threadIdx.x;
  if(e>=E) return;
  const float* f = &ef[(size_t)e*ED];
  float q1=0.f, q2=0.f, q3=0.f;
  #pragma unroll
  for(int i=0;i<ED;i++){
    float fv = f[i];
    q1 = fmaf(fv, a1e[i], q1);
    q2 = fmaf(fv, a2e[i], q2);
    q3 = fmaf(fv, a3e[i], q3);
  }
  int d = dst[e];
  int p = atomicAdd(&cursor[d], 1);
  uint4 A;
  A.x = (unsigned)src[e];
  A.y = __float_as_uint(q1);
  A.z = __float_as_uint(q2);
  A.w = __float_as_uint(q3);
  rec[p] = A;
}

// ---------------- merged setup: x cast | W swizzle | graph counts ----------------
__global__ __launch_bounds__(256) void k_setup(const float* __restrict__ x, unsigned short* __restrict__ xb,
                        const float* __restrict__ W1, const float* __restrict__ W2,
                        const float* __restrict__ W3, unsigned short* __restrict__ Wb,
                        const int* __restrict__ gid, float* __restrict__ cnt,
                        int N, int ncast){
  int b = blockIdx.x;
  if(b < ncast){
    int i = (b*256 + threadIdx.x)*8;
    if(i >= N*HD) return;
    float4 v0 = *(const float4*)&x[i];
    float4 v1 = *(const float4*)&x[i+4];
    uint4 o;
    o.x = f2b(v0.x) | ((unsigned)f2b(v0.y)<<16);
    o.y = f2b(v0.z) | ((unsigned)f2b(v0.w)<<16);
    o.z = f2b(v1.x) | ((unsigned)f2b(v1.y)<<16);
    o.w = f2b(v1.z) | ((unsigned)f2b(v1.w)<<16);
    *(uint4*)&xb[i] = o;
  } else if(b < ncast + 24){
    int idx = (b - ncast)*256 + threadIdx.x;    // 3 * 2048
    if(idx >= 3*2048) return;
    int layer = idx >> 11;
    int r = idx & 2047;
    const float* W = (layer==0)?W1:((layer==1)?W2:W3);
    int lane = r & 63, tile = r >> 6;
    int kt = tile >> 3, nt = tile & 7;
    int qq = lane >> 4, cc = lane & 15;
    int kbase = kt*32 + qq*8;
    int col = nt*16 + cc;
    unsigned short tmp[8];
    #pragma unroll
    for(int j=0;j<8;j++) tmp[j] = f2b(W[(size_t)(kbase+j)*HD + col]);
    uint4 o;
    o.x = tmp[0]|((unsigned)tmp[1]<<16); o.y = tmp[2]|((unsigned)tmp[3]<<16);
    o.z = tmp[4]|((unsigned)tmp[5]<<16); o.w = tmp[6]|((unsigned)tmp[7]<<16);
    *(uint4*)&Wb[(size_t)idx*8] = o;
  } else {
    int g = threadIdx.x;
    if(g >= NG) return;
    int lo=0, hi=N;
    while(lo<hi){ int mid=(lo+hi)>>1; if(gid[mid] < g) lo=mid+1; else hi=mid; }
    int start = lo; lo = start; hi = N;
    while(lo<hi){ int mid=(lo+hi)>>1; if(gid[mid] < g+1) lo=mid+1; else hi=mid; }
    cnt[g] = (float)(lo - start);
  }
}

// ---------------- MFMA GEMM: Zb[M x 128](bf16) = Ab @ W, fused pdots ----------------
__global__ __launch_bounds__(256) void k_gemm_mfma(
    const unsigned short* __restrict__ Ab,
    const unsigned short* __restrict__ Wb,
    unsigned short* __restrict__ Zb,
    const float* __restrict__ avec,
    float* __restrict__ ps, float* __restrict__ pd, int M)
{
  int tid = threadIdx.x;
  int w = tid >> 6, lane = tid & 63;
  int q = lane >> 4, c = lane & 15;
  int rowbase = blockIdx.x*128 + w*32;
  f32x4 acc[2][8];
  #pragma unroll
  for(int t=0;t<2;t++)
    #pragma unroll
    for(int n=0;n<8;n++) acc[t][n] = (f32x4){0.f,0.f,0.f,0.f};

  int r0 = rowbase + c;      if(r0 > M-1) r0 = M-1;
  int r1 = rowbase + 16 + c; if(r1 > M-1) r1 = M-1;
  #pragma unroll
  for(int kt=0; kt<4; kt++){
    int ko = kt*32 + q*8;
    bf16x8 a0 = __builtin_bit_cast(bf16x8, *(const uint4*)&Ab[(size_t)r0*HD + ko]);
    bf16x8 a1 = __builtin_bit_cast(bf16x8, *(const uint4*)&Ab[(size_t)r1*HD + ko]);
    #pragma unroll
    for(int n=0;n<8;n++){
      bf16x8 b = __builtin_bit_cast(bf16x8, *(const uint4*)&Wb[(((size_t)(kt*8+n))*64 + lane)*8]);
      acc[0][n] = __builtin_amdgcn_mfma_f32_16x16x32_bf16(a0, b, acc[0][n], 0,0,0);
      acc[1][n] = __builtin_amdgcn_mfma_f32_16x16x32_bf16(a1, b, acc[1][n], 0,0,0);
    }
  }
  float asv[8], adv[8];
  #pragma unroll
  for(int n=0;n<8;n++){ asv[n] = avec[n*16+c]; adv[n] = avec[HD + n*16+c]; }
  #pragma unroll
  for(int t=0;t<2;t++){
    #pragma unroll
    for(int r=0;r<4;r++){
      int grow = rowbase + t*16 + 4*q + r;
      bool ok = grow < M;
      #pragma unroll
      for(int n=0;n<8;n++){
        if(ok) Zb[(size_t)grow*HD + n*16 + c] = f2b(acc[t][n][r]);
      }
      float pp = 0.f, dd = 0.f;
      #pragma unroll
      for(int n=0;n<8;n++){ pp = fmaf(acc[t][n][r], asv[n], pp); dd = fmaf(acc[t][n][r], adv[n], dd); }
      #pragma unroll
      for(int o=1;o<16;o<<=1){ pp += __shfl_xor(pp,o); dd += __shfl_xor(dd,o); }
      if(ok && c==0){ ps[grow] = pp; pd[grow] = dd; }
    }
  }
}

// ---------------- fused logits + softmax + aggregate + relu + h(bf16) + att ----------------
// Two-phase per 64-edge tile:
//   phase 1: lane j computes weight of edge t0+j (coalesced rec read, 1 exp / 64 edges)
//   phase 2: quad q gathers z[src] for edge jb+q, weight via ds_bpermute from phase-1 regs
__global__ __launch_bounds__(256) void k_agg2(const uint4* __restrict__ zb4,
                                              const int* __restrict__ offs,
                                              const uint4* __restrict__ rec,
                                              const float* __restrict__ ps,
                                              const float* __restrict__ pd,
                                              int layer,
                                              unsigned* __restrict__ hbu,
                                              float* __restrict__ att,
                                              const float* __restrict__ watt,
                                              const float* __restrict__ batt, int N){
  int wid = blockIdx.x*4 + (threadIdx.x>>6);
  int lane = threadIdx.x & 63;
  if(wid >= N) return;
  int q = lane >> 4, c = lane & 15;
  int d0 = offs[wid], d1 = offs[wid+1];
  float pdv = pd[wid];
  float acc[8];
  #pragma unroll
  for(int i=0;i<8;i++) acc[i]=0.f;
  float ssum = 0.f;

  for(int t0=d0; t0<d1; t0+=64){
    int rem = d1 - t0; if(rem > 64) rem = 64;
    // ---- phase 1: per-lane edge weight ----
    int j = t0 + lane;
    float w = 0.f; int u = 0;
    if(j < d1){
      uint4 R = rec[j];
      u = (int)R.x;
      float ql = __uint_as_float(layer==0 ? R.y : (layer==1 ? R.z : R.w));
      float l = ps[u] + pdv + ql;
      l = (l >= 0.f) ? l : 0.2f*l;
      w = __expf(l);
    }
    float ws = w;
    #pragma unroll
    for(int o=32;o;o>>=1) ws += __shfl_xor(ws,o);
    ssum += ws;
    // ---- phase 2: quad-parallel z gather ----
    for(int jb=0; jb<rem; jb+=4){
      int idx = jb + q;                    // < 64 always
      float wgt = bperm_f(idx, w);
      int   uu  = bperm_i(idx, u);
      uint4 P = zb4[(size_t)uu*16 + c];
      acc[0] = fmaf(wgt, blo(P.x), acc[0]); acc[1] = fmaf(wgt, bhi(P.x), acc[1]);
      acc[2] = fmaf(wgt, blo(P.y), acc[2]); acc[3] = fmaf(wgt, bhi(P.y), acc[3]);
      acc[4] = fmaf(wgt, blo(P.z), acc[4]); acc[5] = fmaf(wgt, bhi(P.z), acc[5]);
      acc[6] = fmaf(wgt, blo(P.w), acc[6]); acc[7] = fmaf(wgt, bhi(P.w), acc[7]);
    }
  }
  #pragma unroll
  for(int i=0;i<8;i++){ acc[i] += __shfl_xor(acc[i],16); acc[i] += __shfl_xor(acc[i],32); }
  float inv = (d1 > d0) ? 1.0f/ssum : 0.0f;
  #pragma unroll
  for(int i=0;i<8;i++) acc[i] = fmaxf(acc[i]*inv, 0.f);
  hbu[(size_t)wid*64 + c*4 + q] = (unsigned)f2b(acc[2*q]) | ((unsigned)f2b(acc[2*q+1])<<16);
  float4 w0 = *(const float4*)&watt[c*8];
  float4 w1 = *(const float4*)&watt[c*8+4];
  float t = acc[0]*w0.x + acc[1]*w0.y + acc[2]*w0.z + acc[3]*w0.w
          + acc[4]*w1.x + acc[5]*w1.y + acc[6]*w1.z + acc[7]*w1.w;
  #pragma unroll
  for(int o=1;o<16;o<<=1) t += __shfl_xor(t,o);
  t += batt[0];
  float lr = (t >= 0.f) ? t : 0.01f*t;
  if(lane==0) att[wid] = __expf(lr);
}

// ---------------- readout: hg[g] += att[v] * h[v] ----------------
#define RCH 8
__global__ __launch_bounds__(64) void k_readout(const unsigned* __restrict__ hbu,
                                                const float* __restrict__ att,
                                                const int* __restrict__ gid,
                                                float* __restrict__ hg, int N){
  int g = blockIdx.x / RCH;
  int chunk = blockIdx.x % RCH;
  int t = threadIdx.x;
  int lo=0, hi=N;
  while(lo<hi){ int mid=(lo+hi)>>1; if(gid[mid] < g) lo=mid+1; else hi=mid; }
  int start = lo; lo = start; hi = N;
  while(lo<hi){ int mid=(lo+hi)>>1; if(gid[mid] < g+1) lo=mid+1; else hi=mid; }
  int end = lo;
  int len = end - start;
  int c0 = start + (int)(((long long)len * chunk) / RCH);
  int c1 = start + (int)(((long long)len * (chunk+1)) / RCH);
  float acc0 = 0.f, acc1 = 0.f;
  for(int v=c0; v<c1; v++){
    unsigned P = hbu[(size_t)v*64 + t];
    float a = att[v];
    acc0 = fmaf(a, blo(P), acc0);
    acc1 = fmaf(a, bhi(P), acc1);
  }
  atomicAdd(&hg[g*HD + 2*t],     acc0);
  atomicAdd(&hg[g*HD + 2*t + 1], acc1);
}

// ---------------- final classifier + log_softmax (block per graph) ----------------
__global__ __launch_bounds__(384) void k_final(const float* __restrict__ hg,
                                               const float* __restrict__ cnt,
                                               const float* __restrict__ Wc,
                                               const float* __restrict__ bc,
                                               float* __restrict__ out){
  int g = blockIdx.x;
  int t = threadIdx.x;
  __shared__ float red[6];
  __shared__ float yv[NC];
  float invc = 1.f / fmaxf(cnt[g], 1.f);
  int part = t >> 7;
  int f = t & 127;
  float v = hg[(size_t)part*NG*HD + g*HD + f] * invc;
  for(int c=0; c<NC; c++){
    float p = v * Wc[(size_t)t*NC + c];
    #pragma unroll
    for(int o=32;o;o>>=1) p += __shfl_xor(p,o);
    if((t&63)==0) red[t>>6] = p;
    __syncthreads();
    if(t==0) yv[c] = bc[c] + red[0]+red[1]+red[2]+red[3]+red[4]+red[5];
    __syncthreads();
  }
  if(t==0){
    float mx = -INFINITY;
    #pragma unroll
    for(int c=0;c<NC;c++) mx = fmaxf(mx, yv[c]);
    float s = 0.f;
    #pragma unroll
    for(int c=0;c<NC;c++) s += __expf(yv[c] - mx);
    float ls = logf(s);
    #pragma unroll
    for(int c=0;c<NC;c++) out[g*NC + c] = yv[c] - mx - ls;
  }
}

// ---------------- host ----------------
extern "C" void kernel_launch(void* const* d_in, const int* in_sizes, int n_in,
                              void* d_out, int out_size, void* d_ws, size_t ws_size,
                              hipStream_t stream) {
  const float* x     = (const float*)d_in[0];
  const float* efeat = (const float*)d_in[1];
  const int*   src   = (const int*)d_in[2];
  const int*   dst   = (const int*)d_in[3];
  const int*   gid   = (const int*)d_in[4];
  const float* W1    = (const float*)d_in[5];
  const float* a1    = (const float*)d_in[6];
  const float* W2    = (const float*)d_in[7];
  const float* a2    = (const float*)d_in[8];
  const float* W3    = (const float*)d_in[9];
  const float* a3    = (const float*)d_in[10];
  const float* watt  = (const float*)d_in[11];
  const float* batt  = (const float*)d_in[12];
  const float* Wc    = (const float*)d_in[13];
  const float* bc    = (const float*)d_in[14];
  float* out = (float*)d_out;

  int N = in_sizes[4];
  int E = in_sizes[2];

  char* p = (char*)d_ws;
  auto alloc = [&](size_t bytes)->void*{
    void* r = (void*)p;
    p += (bytes + 255) & ~(size_t)255;
    return r;
  };
  unsigned short* Xb = (unsigned short*)alloc((size_t)N*HD*2);
  unsigned short* Hb = (unsigned short*)alloc((size_t)N*HD*2);
  unsigned short* Zb = (unsigned short*)alloc((size_t)N*HD*2);
  unsigned short* Wball = (unsigned short*)alloc((size_t)3*2048*8*2);
  float* ps      = (float*)alloc((size_t)N*4);
  float* pd      = (float*)alloc((size_t)N*4);
  float* att     = (float*)alloc((size_t)N*4);
  int*   deg     = (int*)  alloc((size_t)N*4);
  int*   offs    = (int*)  alloc((size_t)(N+1)*4);
  int*   cursor  = (int*)  alloc((size_t)N*4);
  uint4* rec     = (uint4*)alloc((size_t)E*16);
  int*   bsum    = (int*)  alloc((size_t)1024*4);
  int*   bbase   = (int*)  alloc((size_t)1024*4);
  float* hg      = (float*)alloc((size_t)3*NG*HD*4);
  float* cnt     = (float*)alloc((size_t)NG*4);
  (void)ws_size; (void)n_in; (void)out_size;

  int ethreads = 256;
  int eblocks = (E + ethreads - 1) / ethreads;
  int nwblocks = (N + 3) / 4;
  int nb = (N + 255) / 256;
  int ncast = (N*16 + 255) / 256;

  hipMemsetAsync(deg, 0, (size_t)N*4, stream);
  hipMemsetAsync(hg, 0, (size_t)3*NG*HD*4, stream);
  k_hist<<<(E/4 + 255)/256, 256, 0, stream>>>(dst, deg, E);
  k_bsum<<<nb, 64, 0, stream>>>(deg, bsum, N);
  k_bscan<<<1, 1024, 0, stream>>>(bsum, bbase, offs, N, nb);
  k_bprop<<<nb, 256, 0, stream>>>(deg, bbase, offs, cursor, N);
  k_scatterq<<<eblocks, ethreads, 0, stream>>>(src, dst, efeat, a1+2*HD, a2+2*HD, a3+2*HD,
                                               cursor, rec, E);
  k_setup<<<ncast + 25, 256, 0, stream>>>(x, Xb, W1, W2, W3, Wball, gid, cnt, N, ncast);

  const float* as[3] = {a1, a2, a3};
  for(int layer=0; layer<3; layer++){
    const unsigned short* Ab = (layer==0) ? Xb : Hb;
    k_gemm_mfma<<<(N+127)/128, 256, 0, stream>>>(Ab, Wball + (size_t)layer*2048*8, Zb,
                                                 as[layer], ps, pd, N);
    k_agg2<<<nwblocks, 256, 0, stream>>>((const uint4*)Zb, offs, rec, ps, pd, layer,
                                         (unsigned*)Hb, att, watt, batt, N);
    k_readout<<<NG*RCH, 64, 0, stream>>>((const unsigned*)Hb, att, gid,
                                         hg + (size_t)layer*NG*HD, N);
  }
  k_final<<<NG, 384, 0, stream>>>(hg, cnt, Wc, bc, out);
}

// Round 9
// 451.366 us; speedup vs baseline: 2.0133x; 1.0816x over previous
//
#include <hip/hip_runtime.h>
#include <math.h>

#define HD 128      // hidden dim (= F_IN)
#define ED 16       // edge feat dim
#define NG 64       // num graphs
#define NC 10       // num classes

typedef short bf16x8 __attribute__((ext_vector_type(8)));
typedef float f32x4 __attribute__((ext_vector_type(4)));

__device__ __forceinline__ unsigned short f2b(float x){
  unsigned u = __float_as_uint(x);
  unsigned r = (u + 0x7fffu + ((u >> 16) & 1u)) >> 16;
  return (unsigned short)r;
}
__device__ __forceinline__ float blo(unsigned p){ return __uint_as_float(p << 16); }
__device__ __forceinline__ float bhi(unsigned p){ return __uint_as_float(p & 0xffff0000u); }
__device__ __forceinline__ float bperm_f(int idx, float v){
  return __int_as_float(__builtin_amdgcn_ds_bpermute(idx<<2, __float_as_int(v)));
}
__device__ __forceinline__ int bperm_i(int idx, int v){
  return __builtin_amdgcn_ds_bpermute(idx<<2, v);
}

// ---------------- CSR build ----------------
__global__ void k_hist(const int* __restrict__ dst, int* __restrict__ deg, int E){
  int e4 = (blockIdx.x*blockDim.x + threadIdx.x)*4;
  if(e4+3 < E){
    int4 d = *(const int4*)&dst[e4];
    atomicAdd(&deg[d.x], 1); atomicAdd(&deg[d.y], 1);
    atomicAdd(&deg[d.z], 1); atomicAdd(&deg[d.w], 1);
  } else {
    for(int k=0;k<4;k++) if(e4+k<E) atomicAdd(&deg[dst[e4+k]], 1);
  }
}

__global__ __launch_bounds__(64) void k_bsum(const int* __restrict__ deg, int* __restrict__ bsum, int N){
  int b = blockIdx.x, t = threadIdx.x;
  int i = b*256 + t*4;
  int s = 0;
  if(i+3 < N){ int4 v = *(const int4*)&deg[i]; s = v.x+v.y+v.z+v.w; }
  else { for(int k=0;k<4;k++) if(i+k<N) s += deg[i+k]; }
  #pragma unroll
  for(int o=32;o;o>>=1) s += __shfl_xor(s,o);
  if(t==0) bsum[b] = s;
}

__global__ __launch_bounds__(1024) void k_bscan(const int* __restrict__ bsum, int* __restrict__ bbase,
                                                int* __restrict__ offs, int N, int nb){
  __shared__ int sh[1024];
  int t = threadIdx.x;
  int v = (t < nb) ? bsum[t] : 0;
  sh[t] = v; __syncthreads();
  for(int o=1;o<1024;o<<=1){ int u = (t>=o)?sh[t-o]:0; __syncthreads(); sh[t]+=u; __syncthreads(); }
  if(t < nb) bbase[t] = sh[t] - v;
  if(t == 1023) offs[N] = sh[1023];
}

__global__ __launch_bounds__(256) void k_bprop(const int* __restrict__ deg, const int* __restrict__ bbase,
                                               int* __restrict__ offs, int* __restrict__ cursor, int N){
  __shared__ int sh[256];
  int b = blockIdx.x, t = threadIdx.x;
  int i = b*256 + t;
  int v = (i<N) ? deg[i] : 0;
  sh[t] = v; __syncthreads();
  for(int o=1;o<256;o<<=1){ int u = (t>=o)?sh[t-o]:0; __syncthreads(); sh[t]+=u; __syncthreads(); }
  if(i<N){ int o_ = bbase[b] + sh[t] - v; offs[i] = o_; cursor[i] = o_; }
}

// ---------------- scatter + fused edge dots: ONE 8B record per edge ----------------
// rec[p] (uint2): x = q1b | q2b<<16 ; y = src(u16) | q3b<<16   (requires N <= 65536)
__global__ void k_scatterq(const int* __restrict__ src, const int* __restrict__ dst,
                           const float* __restrict__ ef,
                           const float* __restrict__ a1e, const float* __restrict__ a2e,
                           const float* __restrict__ a3e,
                           int* __restrict__ cursor, uint2* __restrict__ rec, int E){
  int e = blockIdx.x*blockDim.x + threadIdx.x;
  if(e>=E) return;
  const float* f = &ef[(size_t)e*ED];
  float q1=0.f, q2=0.f, q3=0.f;
  #pragma unroll
  for(int i=0;i<ED;i++){
    float fv = f[i];
    q1 = fmaf(fv, a1e[i], q1);
    q2 = fmaf(fv, a2e[i], q2);
    q3 = fmaf(fv, a3e[i], q3);
  }
  int d = dst[e];
  int p = atomicAdd(&cursor[d], 1);
  uint2 A;
  A.x = (unsigned)f2b(q1) | ((unsigned)f2b(q2) << 16);
  A.y = (unsigned)src[e] | ((unsigned)f2b(q3) << 16);
  rec[p] = A;
}

// ---------------- merged setup: x cast | W swizzle | graph counts ----------------
__global__ __launch_bounds__(256) void k_setup(const float* __restrict__ x, unsigned short* __restrict__ xb,
                        const float* __restrict__ W1, const float* __restrict__ W2,
                        const float* __restrict__ W3, unsigned short* __restrict__ Wb,
                        const int* __restrict__ gid, float* __restrict__ cnt,
                        int N, int ncast){
  int b = blockIdx.x;
  if(b < ncast){
    int i = (b*256 + threadIdx.x)*8;
    if(i >= N*HD) return;
    float4 v0 = *(const float4*)&x[i];
    float4 v1 = *(const float4*)&x[i+4];
    uint4 o;
    o.x = f2b(v0.x) | ((unsigned)f2b(v0.y)<<16);
    o.y = f2b(v0.z) | ((unsigned)f2b(v0.w)<<16);
    o.z = f2b(v1.x) | ((unsigned)f2b(v1.y)<<16);
    o.w = f2b(v1.z) | ((unsigned)f2b(v1.w)<<16);
    *(uint4*)&xb[i] = o;
  } else if(b < ncast + 24){
    int idx = (b - ncast)*256 + threadIdx.x;    // 3 * 2048
    if(idx >= 3*2048) return;
    int layer = idx >> 11;
    int r = idx & 2047;
    const float* W = (layer==0)?W1:((layer==1)?W2:W3);
    int lane = r & 63, tile = r >> 6;
    int kt = tile >> 3, nt = tile & 7;
    int qq = lane >> 4, cc = lane & 15;
    int kbase = kt*32 + qq*8;
    int col = nt*16 + cc;
    unsigned short tmp[8];
    #pragma unroll
    for(int j=0;j<8;j++) tmp[j] = f2b(W[(size_t)(kbase+j)*HD + col]);
    uint4 o;
    o.x = tmp[0]|((unsigned)tmp[1]<<16); o.y = tmp[2]|((unsigned)tmp[3]<<16);
    o.z = tmp[4]|((unsigned)tmp[5]<<16); o.w = tmp[6]|((unsigned)tmp[7]<<16);
    *(uint4*)&Wb[(size_t)idx*8] = o;
  } else {
    int g = threadIdx.x;
    if(g >= NG) return;
    int lo=0, hi=N;
    while(lo<hi){ int mid=(lo+hi)>>1; if(gid[mid] < g) lo=mid+1; else hi=mid; }
    int start = lo; lo = start; hi = N;
    while(lo<hi){ int mid=(lo+hi)>>1; if(gid[mid] < g+1) lo=mid+1; else hi=mid; }
    cnt[g] = (float)(lo - start);
  }
}

// ---------------- MFMA GEMM: Zb[M x 128](bf16) = Ab @ W, fused pdots ----------------
__global__ __launch_bounds__(256) void k_gemm_mfma(
    const unsigned short* __restrict__ Ab,
    const unsigned short* __restrict__ Wb,
    unsigned short* __restrict__ Zb,
    const float* __restrict__ avec,
    float* __restrict__ ps, float* __restrict__ pd, int M)
{
  int tid = threadIdx.x;
  int w = tid >> 6, lane = tid & 63;
  int q = lane >> 4, c = lane & 15;
  int rowbase = blockIdx.x*128 + w*32;
  f32x4 acc[2][8];
  #pragma unroll
  for(int t=0;t<2;t++)
    #pragma unroll
    for(int n=0;n<8;n++) acc[t][n] = (f32x4){0.f,0.f,0.f,0.f};

  int r0 = rowbase + c;      if(r0 > M-1) r0 = M-1;
  int r1 = rowbase + 16 + c; if(r1 > M-1) r1 = M-1;
  #pragma unroll
  for(int kt=0; kt<4; kt++){
    int ko = kt*32 + q*8;
    bf16x8 a0 = __builtin_bit_cast(bf16x8, *(const uint4*)&Ab[(size_t)r0*HD + ko]);
    bf16x8 a1 = __builtin_bit_cast(bf16x8, *(const uint4*)&Ab[(size_t)r1*HD + ko]);
    #pragma unroll
    for(int n=0;n<8;n++){
      bf16x8 b = __builtin_bit_cast(bf16x8, *(const uint4*)&Wb[(((size_t)(kt*8+n))*64 + lane)*8]);
      acc[0][n] = __builtin_amdgcn_mfma_f32_16x16x32_bf16(a0, b, acc[0][n], 0,0,0);
      acc[1][n] = __builtin_amdgcn_mfma_f32_16x16x32_bf16(a1, b, acc[1][n], 0,0,0);
    }
  }
  float asv[8], adv[8];
  #pragma unroll
  for(int n=0;n<8;n++){ asv[n] = avec[n*16+c]; adv[n] = avec[HD + n*16+c]; }
  #pragma unroll
  for(int t=0;t<2;t++){
    #pragma unroll
    for(int r=0;r<4;r++){
      int grow = rowbase + t*16 + 4*q + r;
      bool ok = grow < M;
      #pragma unroll
      for(int n=0;n<8;n++){
        if(ok) Zb[(size_t)grow*HD + n*16 + c] = f2b(acc[t][n][r]);
      }
      float pp = 0.f, dd = 0.f;
      #pragma unroll
      for(int n=0;n<8;n++){ pp = fmaf(acc[t][n][r], asv[n], pp); dd = fmaf(acc[t][n][r], adv[n], dd); }
      #pragma unroll
      for(int o=1;o<16;o<<=1){ pp += __shfl_xor(pp,o); dd += __shfl_xor(dd,o); }
      if(ok && c==0){ ps[grow] = pp; pd[grow] = dd; }
    }
  }
}

// ---------------- fused logits + softmax + aggregate + relu + h(bf16) + att ----------------
// phase 1: lane j = weight of edge t0+j (coalesced 8B rec, 1 exp / 64 edges)
// phase 2: unrolled x4 — 16 edges in flight per iteration (4 gathers/lane)
__global__ __launch_bounds__(256) void k_agg2(const uint4* __restrict__ zb4,
                                              const int* __restrict__ offs,
                                              const uint2* __restrict__ rec,
                                              const float* __restrict__ ps,
                                              const float* __restrict__ pd,
                                              int layer,
                                              unsigned* __restrict__ hbu,
                                              float* __restrict__ att,
                                              const float* __restrict__ watt,
                                              const float* __restrict__ batt, int N){
  int wid = blockIdx.x*4 + (threadIdx.x>>6);
  int lane = threadIdx.x & 63;
  if(wid >= N) return;
  int q = lane >> 4, c = lane & 15;
  int d0 = offs[wid], d1 = offs[wid+1];
  float pdv = pd[wid];
  float acc[8];
  #pragma unroll
  for(int i=0;i<8;i++) acc[i]=0.f;
  float ssum = 0.f;

  for(int t0=d0; t0<d1; t0+=64){
    int rem = d1 - t0; if(rem > 64) rem = 64;
    // ---- phase 1: per-lane edge weight ----
    int j = t0 + lane;
    float w = 0.f; int u = 0;
    if(j < d1){
      uint2 R = rec[j];
      u = (int)(R.y & 0xffffu);
      unsigned qb = (layer==0) ? (R.x & 0xffffu) : (layer==1 ? (R.x >> 16) : (R.y >> 16));
      float ql = __uint_as_float(qb << 16);
      float l = ps[u] + pdv + ql;
      l = (l >= 0.f) ? l : 0.2f*l;
      w = __expf(l);
    }
    float ws = w;
    #pragma unroll
    for(int o=32;o;o>>=1) ws += __shfl_xor(ws,o);
    ssum += ws;
    // ---- phase 2: 16 edges per iteration (lanes beyond rem have w=0 -> no guard) ----
    for(int jb=0; jb<rem; jb+=16){
      float w0 = bperm_f(jb+q,    w);  int u0 = bperm_i(jb+q,    u);
      float w1 = bperm_f(jb+4+q,  w);  int u1 = bperm_i(jb+4+q,  u);
      float w2 = bperm_f(jb+8+q,  w);  int u2 = bperm_i(jb+8+q,  u);
      float w3 = bperm_f(jb+12+q, w);  int u3 = bperm_i(jb+12+q, u);
      uint4 P0 = zb4[(size_t)u0*16 + c];
      uint4 P1 = zb4[(size_t)u1*16 + c];
      uint4 P2 = zb4[(size_t)u2*16 + c];
      uint4 P3 = zb4[(size_t)u3*16 + c];
      acc[0] = fmaf(w0, blo(P0.x), acc[0]); acc[1] = fmaf(w0, bhi(P0.x), acc[1]);
      acc[2] = fmaf(w0, blo(P0.y), acc[2]); acc[3] = fmaf(w0, bhi(P0.y), acc[3]);
      acc[4] = fmaf(w0, blo(P0.z), acc[4]); acc[5] = fmaf(w0, bhi(P0.z), acc[5]);
      acc[6] = fmaf(w0, blo(P0.w), acc[6]); acc[7] = fmaf(w0, bhi(P0.w), acc[7]);
      acc[0] = fmaf(w1, blo(P1.x), acc[0]); acc[1] = fmaf(w1, bhi(P1.x), acc[1]);
      acc[2] = fmaf(w1, blo(P1.y), acc[2]); acc[3] = fmaf(w1, bhi(P1.y), acc[3]);
      acc[4] = fmaf(w1, blo(P1.z), acc[4]); acc[5] = fmaf(w1, bhi(P1.z), acc[5]);
      acc[6] = fmaf(w1, blo(P1.w), acc[6]); acc[7] = fmaf(w1, bhi(P1.w), acc[7]);
      acc[0] = fmaf(w2, blo(P2.x), acc[0]); acc[1] = fmaf(w2, bhi(P2.x), acc[1]);
      acc[2] = fmaf(w2, blo(P2.y), acc[2]); acc[3] = fmaf(w2, bhi(P2.y), acc[3]);
      acc[4] = fmaf(w2, blo(P2.z), acc[4]); acc[5] = fmaf(w2, bhi(P2.z), acc[5]);
      acc[6] = fmaf(w2, blo(P2.w), acc[6]); acc[7] = fmaf(w2, bhi(P2.w), acc[7]);
      acc[0] = fmaf(w3, blo(P3.x), acc[0]); acc[1] = fmaf(w3, bhi(P3.x), acc[1]);
      acc[2] = fmaf(w3, blo(P3.y), acc[2]); acc[3] = fmaf(w3, bhi(P3.y), acc[3]);
      acc[4] = fmaf(w3, blo(P3.z), acc[4]); acc[5] = fmaf(w3, bhi(P3.z), acc[5]);
      acc[6] = fmaf(w3, blo(P3.w), acc[6]); acc[7] = fmaf(w3, bhi(P3.w), acc[7]);
    }
  }
  #pragma unroll
  for(int i=0;i<8;i++){ acc[i] += __shfl_xor(acc[i],16); acc[i] += __shfl_xor(acc[i],32); }
  float inv = (d1 > d0) ? 1.0f/ssum : 0.0f;
  #pragma unroll
  for(int i=0;i<8;i++) acc[i] = fmaxf(acc[i]*inv, 0.f);
  hbu[(size_t)wid*64 + c*4 + q] = (unsigned)f2b(acc[2*q]) | ((unsigned)f2b(acc[2*q+1])<<16);
  float4 w0v = *(const float4*)&watt[c*8];
  float4 w1v = *(const float4*)&watt[c*8+4];
  float t = acc[0]*w0v.x + acc[1]*w0v.y + acc[2]*w0v.z + acc[3]*w0v.w
          + acc[4]*w1v.x + acc[5]*w1v.y + acc[6]*w1v.z + acc[7]*w1v.w;
  #pragma unroll
  for(int o=1;o<16;o<<=1) t += __shfl_xor(t,o);
  t += batt[0];
  float lr = (t >= 0.f) ? t : 0.01f*t;
  if(lane==0) att[wid] = __expf(lr);
}

// ---------------- readout: hg[g] += att[v] * h[v] ----------------
#define RCH 16
__global__ __launch_bounds__(64) void k_readout(const unsigned* __restrict__ hbu,
                                                const float* __restrict__ att,
                                                const int* __restrict__ gid,
                                                float* __restrict__ hg, int N){
  int g = blockIdx.x / RCH;
  int chunk = blockIdx.x % RCH;
  int t = threadIdx.x;
  int lo=0, hi=N;
  while(lo<hi){ int mid=(lo+hi)>>1; if(gid[mid] < g) lo=mid+1; else hi=mid; }
  int start = lo; lo = start; hi = N;
  while(lo<hi){ int mid=(lo+hi)>>1; if(gid[mid] < g+1) lo=mid+1; else hi=mid; }
  int end = lo;
  int len = end - start;
  int c0 = start + (int)(((long long)len * chunk) / RCH);
  int c1 = start + (int)(((long long)len * (chunk+1)) / RCH);
  float acc0 = 0.f, acc1 = 0.f;
  for(int v=c0; v<c1; v++){
    unsigned P = hbu[(size_t)v*64 + t];
    float a = att[v];
    acc0 = fmaf(a, blo(P), acc0);
    acc1 = fmaf(a, bhi(P), acc1);
  }
  atomicAdd(&hg[g*HD + 2*t],     acc0);
  atomicAdd(&hg[g*HD + 2*t + 1], acc1);
}

// ---------------- final classifier + log_softmax (block per graph) ----------------
__global__ __launch_bounds__(384) void k_final(const float* __restrict__ hg,
                                               const float* __restrict__ cnt,
                                               const float* __restrict__ Wc,
                                               const float* __restrict__ bc,
                                               float* __restrict__ out){
  int g = blockIdx.x;
  int t = threadIdx.x;
  __shared__ float red[6];
  __shared__ float yv[NC];
  float invc = 1.f / fmaxf(cnt[g], 1.f);
  int part = t >> 7;
  int f = t & 127;
  float v = hg[(size_t)part*NG*HD + g*HD + f] * invc;
  for(int c=0; c<NC; c++){
    float p = v * Wc[(size_t)t*NC + c];
    #pragma unroll
    for(int o=32;o;o>>=1) p += __shfl_xor(p,o);
    if((t&63)==0) red[t>>6] = p;
    __syncthreads();
    if(t==0) yv[c] = bc[c] + red[0]+red[1]+red[2]+red[3]+red[4]+red[5];
    __syncthreads();
  }
  if(t==0){
    float mx = -INFINITY;
    #pragma unroll
    for(int c=0;c<NC;c++) mx = fmaxf(mx, yv[c]);
    float s = 0.f;
    #pragma unroll
    for(int c=0;c<NC;c++) s += __expf(yv[c] - mx);
    float ls = logf(s);
    #pragma unroll
    for(int c=0;c<NC;c++) out[g*NC + c] = yv[c] - mx - ls;
  }
}

// ---------------- host ----------------
extern "C" void kernel_launch(void* const* d_in, const int* in_sizes, int n_in,
                              void* d_out, int out_size, void* d_ws, size_t ws_size,
                              hipStream_t stream) {
  const float* x     = (const float*)d_in[0];
  const float* efeat = (const float*)d_in[1];
  const int*   src   = (const int*)d_in[2];
  const int*   dst   = (const int*)d_in[3];
  const int*   gid   = (const int*)d_in[4];
  const float* W1    = (const float*)d_in[5];
  const float* a1    = (const float*)d_in[6];
  const float* W2    = (const float*)d_in[7];
  const float* a2    = (const float*)d_in[8];
  const float* W3    = (const float*)d_in[9];
  const float* a3    = (const float*)d_in[10];
  const float* watt  = (const float*)d_in[11];
  const float* batt  = (const float*)d_in[12];
  const float* Wc    = (const float*)d_in[13];
  const float* bc    = (const float*)d_in[14];
  float* out = (float*)d_out;

  int N = in_sizes[4];
  int E = in_sizes[2];

  char* p = (char*)d_ws;
  auto alloc = [&](size_t bytes)->void*{
    void* r = (void*)p;
    p += (bytes + 255) & ~(size_t)255;
    return r;
  };
  unsigned short* Xb = (unsigned short*)alloc((size_t)N*HD*2);
  unsigned short* Hb = (unsigned short*)alloc((size_t)N*HD*2);
  unsigned short* Zb = (unsigned short*)alloc((size_t)N*HD*2);
  unsigned short* Wball = (unsigned short*)alloc((size_t)3*2048*8*2);
  float* ps      = (float*)alloc((size_t)N*4);
  float* pd      = (float*)alloc((size_t)N*4);
  float* att     = (float*)alloc((size_t)N*4);
  int*   deg     = (int*)  alloc((size_t)N*4);
  int*   offs    = (int*)  alloc((size_t)(N+1)*4);
  int*   cursor  = (int*)  alloc((size_t)N*4);
  uint2* rec     = (uint2*)alloc((size_t)E*8);
  int*   bsum    = (int*)  alloc((size_t)1024*4);
  int*   bbase   = (int*)  alloc((size_t)1024*4);
  float* hg      = (float*)alloc((size_t)3*NG*HD*4);
  float* cnt     = (float*)alloc((size_t)NG*4);
  (void)ws_size; (void)n_in; (void)out_size;

  int ethreads = 256;
  int eblocks = (E + ethreads - 1) / ethreads;
  int nwblocks = (N + 3) / 4;
  int nb = (N + 255) / 256;
  int ncast = (N*16 + 255) / 256;

  hipMemsetAsync(deg, 0, (size_t)N*4, stream);
  hipMemsetAsync(hg, 0, (size_t)3*NG*HD*4, stream);
  k_hist<<<(E/4 + 255)/256, 256, 0, stream>>>(dst, deg, E);
  k_bsum<<<nb, 64, 0, stream>>>(deg, bsum, N);
  k_bscan<<<1, 1024, 0, stream>>>(bsum, bbase, offs, N, nb);
  k_bprop<<<nb, 256, 0, stream>>>(deg, bbase, offs, cursor, N);
  k_scatterq<<<eblocks, ethreads, 0, stream>>>(src, dst, efeat, a1+2*HD, a2+2*HD, a3+2*HD,
                                               cursor, rec, E);
  k_setup<<<ncast + 25, 256, 0, stream>>>(x, Xb, W1, W2, W3, Wball, gid, cnt, N, ncast);

  const float* as[3] = {a1, a2, a3};
  for(int layer=0; layer<3; layer++){
    const unsigned short* Ab = (layer==0) ? Xb : Hb;
    k_gemm_mfma<<<(N+127)/128, 256, 0, stream>>>(Ab, Wball + (size_t)layer*2048*8, Zb,
                                                 as[layer], ps, pd, N);
    k_agg2<<<nwblocks, 256, 0, stream>>>((const uint4*)Zb, offs, rec, ps, pd, layer,
                                         (unsigned*)Hb, att, watt, batt, N);
    k_readout<<<NG*RCH, 64, 0, stream>>>((const unsigned*)Hb, att, gid,
                                         hg + (size_t)layer*NG*HD, N);
  }
  k_final<<<NG, 384, 0, stream>>>(hg, cnt, Wc, bc, out);
}